// Round 7
// baseline (251.144 us; speedup 1.0000x reference)
//
#include <hip/hip_runtime.h>
#include <hip/hip_bf16.h>

// Problem constants (from reference)
#define C_CH   128
#define DROW   1152          // C * (1+3+5)
#define NNODE  8192          // B*M
#define BATCH  16
#define MSEQ   512
#define NHEAD  8
#define HD     144           // DROW / NHEAD
#define NEDGE  262144

typedef unsigned short ushort_t;
typedef __attribute__((ext_vector_type(8))) short bf16x8;
typedef __attribute__((ext_vector_type(4))) float f32x4;

__device__ __forceinline__ float ldf(const float* p) { return *p; }
__device__ __forceinline__ float ldf(const __hip_bfloat16* p) { return __bfloat162float(*p); }
__device__ __forceinline__ ushort_t f2bu(float x) {
    __hip_bfloat16 h = __float2bfloat16(x);
    return *reinterpret_cast<ushort_t*>(&h);
}
__device__ __forceinline__ float bu2f(ushort_t u) {
    return __bfloat162float(*reinterpret_cast<__hip_bfloat16*>(&u));
}
// static-index halfword extract from a uint4 held in registers (no memory)
__device__ __forceinline__ unsigned u16of(const uint4 v, int ii) {
    const unsigned w = ((ii >> 1) == 0) ? v.x : ((ii >> 1) == 1) ? v.y :
                       ((ii >> 1) == 2) ? v.z : v.w;
    return (ii & 1) ? (w >> 16) : (w & 0xFFFFu);
}

#define KP2 136   // LDS row elems for K=128 (+8 pad)

// ---------------------------------------------------------------------------
// Fused QKV: ONE kernel, all three l-levels, X read ONCE per block.
// 16 nodes/block -> 144 GEMM columns: [0,16) l0 | [16,64) l1 | [64,144) l2
// (col = colbase_l + nb*DL + m, exactly round-0's per-l column layout).
// Round-0 z-loop over {Wq,Wk,Wv}; per z three unrolled l-groups load their
// W frags and run their tiles. Per output element the fragment contents,
// kst accumulation order and rounding match round 0 => bitwise-identical.
// Traffic: X 37.7 MB (was 113), writes 56.6 MB. No bx-branching (R1/R2
// failure shape avoided): single uniform code path.
// ---------------------------------------------------------------------------
__global__ __launch_bounds__(256) void qkv_fused(
    const float* __restrict__ X,
    const float* __restrict__ Wq, const float* __restrict__ Wk,
    const float* __restrict__ Wv,
    __hip_bfloat16* __restrict__ Yq, __hip_bfloat16* __restrict__ Yk,
    __hip_bfloat16* __restrict__ Yv)
{
    __shared__ __align__(16) ushort_t Xs[144][KP2];   // 39168 B
    __shared__ __align__(16) ushort_t Es[144][KP2];   // 39168 B

    const int tid  = threadIdx.x;
    const int wave = tid >> 6;
    const int lane = tid & 63;
    const int l15  = lane & 15;
    const int quad = lane >> 4;
    const int n0   = blockIdx.x * 16;

    // ---- stage X^T for all l: Xs[col][c] ----
    for (int e4 = tid; e4 < 16 * 288; e4 += 256) {
        const int nb = e4 / 288;
        const int rr = (e4 - nb * 288) * 4;
        const float4 xv = *reinterpret_cast<const float4*>(
            &X[(size_t)(n0 + nb) * DROW + rr]);
        #pragma unroll
        for (int j = 0; j < 4; ++j) {
            const int r = rr + j;
            int col, c;
            if (r < 128)      { col = nb; c = r; }
            else if (r < 512) { const int t = r - 128; c = t / 3; col = 16 + nb * 3 + (t - c * 3); }
            else              { const int t = r - 512; c = t / 5; col = 64 + nb * 5 + (t - c * 5); }
            Xs[col][c] = f2bu(reinterpret_cast<const float*>(&xv)[j]);
        }
    }

    const float s = 0.08838834764831845f;      // 1/sqrt(128)

    __syncthreads();   // Xs staged

    for (int z = 0; z < 3; ++z) {
        const float* Wz        = (z == 0) ? Wq : (z == 1 ? Wk : Wv);
        __hip_bfloat16* Y      = (z == 0) ? Yq : (z == 1 ? Yk : Yv);

        f32x4 acc[9][2];
        #pragma unroll
        for (int ct = 0; ct < 9; ++ct) {
            acc[ct][0] = (f32x4){0.f, 0.f, 0.f, 0.f};
            acc[ct][1] = (f32x4){0.f, 0.f, 0.f, 0.f};
        }

        // three l-groups, statically unrolled; aw reloaded per group
        #pragma unroll
        for (int lg = 0; lg < 3; ++lg) {
            const int woff   = lg * 16384;
            const int ctlo   = (lg == 0) ? 0 : (lg == 1 ? 1 : 4);
            const int cthi   = (lg == 0) ? 1 : (lg == 1 ? 4 : 9);
            const float* W   = Wz + woff;

            bf16x8 aw[2][4];
            #pragma unroll
            for (int ot = 0; ot < 2; ++ot)
                #pragma unroll
                for (int kst = 0; kst < 4; ++kst) {
                    const float* wp = &W[(size_t)(32 * wave + 16 * ot + l15) * 128 + kst * 32 + quad * 8];
                    const float4 wa = *reinterpret_cast<const float4*>(wp);
                    const float4 wb = *reinterpret_cast<const float4*>(wp + 4);
                    ushort_t t[8] = {f2bu(wa.x), f2bu(wa.y), f2bu(wa.z), f2bu(wa.w),
                                     f2bu(wb.x), f2bu(wb.y), f2bu(wb.z), f2bu(wb.w)};
                    aw[ot][kst] = *reinterpret_cast<const bf16x8*>(t);
                }

            #pragma unroll
            for (int kst = 0; kst < 4; ++kst)
                #pragma unroll 9
                for (int ct = ctlo; ct < cthi; ++ct) {
                    const bf16x8 b = *reinterpret_cast<const bf16x8*>(
                        &Xs[ct * 16 + l15][kst * 32 + quad * 8]);
                    acc[ct][0] = __builtin_amdgcn_mfma_f32_16x16x32_bf16(aw[0][kst], b, acc[ct][0], 0, 0, 0);
                    acc[ct][1] = __builtin_amdgcn_mfma_f32_16x16x32_bf16(aw[1][kst], b, acc[ct][1], 0, 0, 0);
                }
        }

        // C -> Es[col][o] (scale applied here)
        #pragma unroll
        for (int ct = 0; ct < 9; ++ct)
            #pragma unroll
            for (int ot = 0; ot < 2; ++ot) {
                ushort_t t[4] = {f2bu(acc[ct][ot][0] * s), f2bu(acc[ct][ot][1] * s),
                                 f2bu(acc[ct][ot][2] * s), f2bu(acc[ct][ot][3] * s)};
                *reinterpret_cast<uint2*>(&Es[ct * 16 + l15][32 * wave + 16 * ot + quad * 4]) =
                    *reinterpret_cast<const uint2*>(t);
            }
        __syncthreads();

        // coalesced store: contiguous spans of 8 output elems (128/512 are
        // multiples of 8 so a span never crosses an l boundary)
        for (int e8 = tid; e8 < 16 * 144; e8 += 256) {
            const int nb = e8 / 144;
            const int rr = (e8 - nb * 144) * 8;
            ushort_t t[8];
            #pragma unroll
            for (int j = 0; j < 8; ++j) {
                const int r = rr + j;
                int col, o;
                if (r < 128)      { col = nb; o = r; }
                else if (r < 512) { const int u = r - 128; o = u / 3; col = 16 + nb * 3 + (u - o * 3); }
                else              { const int u = r - 512; o = u / 5; col = 64 + nb * 5 + (u - o * 5); }
                t[j] = Es[col][o];
            }
            *reinterpret_cast<uint4*>(&Y[(size_t)(n0 + nb) * DROW + rr]) =
                *reinterpret_cast<const uint4*>(t);
        }
        __syncthreads();   // Es reads done before next z overwrites
    }
}

// ---------------------------------------------------------------------------
// irreps_linear as one GEMM per l — ROUND-0 VERBATIM (used by OUT linears).
// ---------------------------------------------------------------------------
template<int DL, int NPB, int NZ, int FUSE_LN, typename TX, typename TY>
__global__ __launch_bounds__(256) void lin_mfma(
    const TX* __restrict__ X,
    const float* __restrict__ W0, const float* __restrict__ W1,
    const float* __restrict__ W2,
    TY* __restrict__ Y0, TY* __restrict__ Y1, TY* __restrict__ Y2,
    const float* __restrict__ resid,
    const float* __restrict__ gamma, const float* __restrict__ beta,
    int baseoff)
{
    constexpr int COLS = NPB * DL;     // GEMM columns per block (multiple of 16)
    constexpr int CT   = COLS / 16;
    __shared__ __align__(16) ushort_t Xs[COLS][KP2];
    __shared__ __align__(16) ushort_t Es[COLS][KP2];

    const int tid  = threadIdx.x;
    const int wave = tid >> 6;
    const int lane = tid & 63;
    const int l15  = lane & 15;
    const int quad = lane >> 4;
    const int n0   = blockIdx.x * NPB;

    // ---- stage X^T: Xs[nb*DL + m][c] = X[n0+nb, baseoff + c*DL + m] ----
    if constexpr (sizeof(TX) == 4) {
        for (int e4 = tid; e4 < NPB * 32 * DL; e4 += 256) {
            const int nb = e4 / (32 * DL);
            const int rr = (e4 - nb * (32 * DL)) * 4;
            const float4 xv = *reinterpret_cast<const float4*>(
                &X[(size_t)(n0 + nb) * DROW + baseoff + rr]);
            #pragma unroll
            for (int j = 0; j < 4; ++j) {
                const int r = rr + j, c = r / DL, m = r - c * DL;
                Xs[nb * DL + m][c] = f2bu(reinterpret_cast<const float*>(&xv)[j]);
            }
        }
    } else {
        for (int e8 = tid; e8 < NPB * 16 * DL; e8 += 256) {
            const int nb = e8 / (16 * DL);
            const int rr = (e8 - nb * (16 * DL)) * 8;
            const uint4 xv = *reinterpret_cast<const uint4*>(
                &X[(size_t)(n0 + nb) * DROW + baseoff + rr]);
            const ushort_t* xs = reinterpret_cast<const ushort_t*>(&xv);
            #pragma unroll
            for (int j = 0; j < 8; ++j) {
                const int r = rr + j, c = r / DL, m = r - c * DL;
                Xs[nb * DL + m][c] = xs[j];
            }
        }
    }

    const float s = 0.08838834764831845f;      // 1/sqrt(128)

    for (int z = 0; z < NZ; ++z) {
        const float* W = (z == 0) ? W0 : (z == 1 ? W1 : W2);
        TY* Y          = (z == 0) ? Y0 : (z == 1 ? Y1 : Y2);

        // W fragments -> registers (wave owns o in [32w, 32w+32))
        bf16x8 aw[2][4];
        #pragma unroll
        for (int ot = 0; ot < 2; ++ot)
            #pragma unroll
            for (int kst = 0; kst < 4; ++kst) {
                const float* wp = &W[(size_t)(32 * wave + 16 * ot + l15) * 128 + kst * 32 + quad * 8];
                const float4 wa = *reinterpret_cast<const float4*>(wp);
                const float4 wb = *reinterpret_cast<const float4*>(wp + 4);
                ushort_t t[8] = {f2bu(wa.x), f2bu(wa.y), f2bu(wa.z), f2bu(wa.w),
                                 f2bu(wb.x), f2bu(wb.y), f2bu(wb.z), f2bu(wb.w)};
                aw[ot][kst] = *reinterpret_cast<const bf16x8*>(t);
            }

        __syncthreads();   // Xs staged (z=0); prev z's Es reads done (z>0)

        f32x4 acc[CT][2];
        #pragma unroll
        for (int ct = 0; ct < CT; ++ct) {
            acc[ct][0] = (f32x4){0.f, 0.f, 0.f, 0.f};
            acc[ct][1] = (f32x4){0.f, 0.f, 0.f, 0.f};
        }
        #pragma unroll
        for (int kst = 0; kst < 4; ++kst)
            #pragma unroll
            for (int ct = 0; ct < CT; ++ct) {
                const bf16x8 b = *reinterpret_cast<const bf16x8*>(
                    &Xs[ct * 16 + l15][kst * 32 + quad * 8]);
                acc[ct][0] = __builtin_amdgcn_mfma_f32_16x16x32_bf16(aw[0][kst], b, acc[ct][0], 0, 0, 0);
                acc[ct][1] = __builtin_amdgcn_mfma_f32_16x16x32_bf16(aw[1][kst], b, acc[ct][1], 0, 0, 0);
            }

        // C -> Es[col][o] (scale applied here)
        #pragma unroll
        for (int ct = 0; ct < CT; ++ct)
            #pragma unroll
            for (int ot = 0; ot < 2; ++ot) {
                ushort_t t[4] = {f2bu(acc[ct][ot][0] * s), f2bu(acc[ct][ot][1] * s),
                                 f2bu(acc[ct][ot][2] * s), f2bu(acc[ct][ot][3] * s)};
                *reinterpret_cast<uint2*>(&Es[ct * 16 + l15][32 * wave + 16 * ot + quad * 4]) =
                    *reinterpret_cast<const uint2*>(t);
            }
        __syncthreads();

        if constexpr (FUSE_LN) {
            // DL==1, NPB==64: 4 lanes per node, 32 channels each
            const int nb = tid >> 2, cc = tid & 3;
            float y[32];
            const float* xr = resid + (size_t)(n0 + nb) * DROW + cc * 32;
            float s1 = 0.f, s2 = 0.f;
            #pragma unroll
            for (int j4 = 0; j4 < 8; ++j4) {
                const float4 rv = *reinterpret_cast<const float4*>(xr + j4 * 4);
                #pragma unroll
                for (int j = 0; j < 4; ++j) {
                    const float v = bu2f(Es[nb][cc * 32 + j4 * 4 + j]) +
                                    reinterpret_cast<const float*>(&rv)[j];
                    y[j4 * 4 + j] = v; s1 += v; s2 += v * v;
                }
            }
            s1 += __shfl_xor(s1, 1); s2 += __shfl_xor(s2, 1);
            s1 += __shfl_xor(s1, 2); s2 += __shfl_xor(s2, 2);
            const float mean = s1 * (1.0f / 128.0f);
            const float var  = s2 * (1.0f / 128.0f) - mean * mean;
            const float rstd = rsqrtf(var + 1e-5f);
            float* op = (float*)Y + (size_t)(n0 + nb) * DROW + cc * 32;
            #pragma unroll
            for (int j4 = 0; j4 < 8; ++j4) {
                float4 ov;
                #pragma unroll
                for (int j = 0; j < 4; ++j) {
                    const int c = cc * 32 + j4 * 4 + j;
                    float t = (y[j4 * 4 + j] - mean) * rstd * gamma[c] + beta[c];
                    reinterpret_cast<float*>(&ov)[j] = t / (1.0f + __expf(-t));
                }
                *reinterpret_cast<float4*>(op + j4 * 4) = ov;
            }
        } else {
            // coalesced store: contiguous spans of 8 output elems r = o*DL+m
            for (int e8 = tid; e8 < COLS * 16; e8 += 256) {
                const int nb = e8 / (16 * DL);
                const int r0 = (e8 - nb * (16 * DL)) * 8;
                const size_t ga = (size_t)(n0 + nb) * DROW + baseoff + r0;
                if constexpr (sizeof(TY) == 2) {
                    ushort_t t[8];
                    #pragma unroll
                    for (int j = 0; j < 8; ++j) {
                        const int r = r0 + j;
                        t[j] = Es[nb * DL + r % DL][r / DL];
                    }
                    *reinterpret_cast<uint4*>(&Y[ga]) = *reinterpret_cast<const uint4*>(t);
                } else {
                    #pragma unroll
                    for (int j4 = 0; j4 < 2; ++j4) {
                        const float4 rv = *reinterpret_cast<const float4*>(&resid[ga + j4 * 4]);
                        float4 ov;
                        #pragma unroll
                        for (int j = 0; j < 4; ++j) {
                            const int r = r0 + j4 * 4 + j;
                            reinterpret_cast<float*>(&ov)[j] =
                                bu2f(Es[nb * DL + r % DL][r / DL]) +
                                reinterpret_cast<const float*>(&rv)[j];
                        }
                        *reinterpret_cast<float4*>(&((float*)Y)[ga + j4 * 4]) = ov;
                    }
                }
            }
        }
    }
}

// ---------------------------------------------------------------------------
// One-pass MFMA attention — ROUND-5 VERBATIM (T14 register-true prefetch).
// ---------------------------------------------------------------------------
#define KPAD  168   // ksqs row elems (144 data + 16 zero-pad + 8)
#define VROWS 160   // 144 V-cols + ones-row + 15 zero rows
#define VPAD2 72    // vst row elems (64 keys + 8)
#define PPAD  68    // ps row elems (64 keys + 4)

__global__ __launch_bounds__(256, 2) void attn_kernel(
    const __hip_bfloat16* __restrict__ Q, const __hip_bfloat16* __restrict__ K,
    const __hip_bfloat16* __restrict__ V, __hip_bfloat16* __restrict__ O)
{
    __shared__ __align__(16) ushort_t ksqs[64][KPAD];   // 21504 B
    __shared__ __align__(16) ushort_t vst[VROWS][VPAD2];// 23040 B
    __shared__ __align__(16) ushort_t ps[128][PPAD];    // 17408 B

    const int tid  = threadIdx.x;
    const int wave = tid >> 6;
    const int lane = tid & 63;
    const int l15  = lane & 15;
    const int quad = lane >> 4;

    const int bid = blockIdx.x;
    const int xcd = bid & 7;
    const int j   = bid >> 3;              // 0..63
    const int bh  = xcd * 16 + (j >> 2);   // 0..127
    const int q0  = (j & 3) * 128;
    const int h   = bh & 7;
    const int b   = bh >> 3;
    const size_t rowbase = (size_t)b * MSEQ * DROW + (size_t)h * HD;
    const float EXSCALE = 0.12022458674074695f;   // log2(e)/sqrt(144)

    // ---- per-thread staging geometry (computed once) ----
    const int r0 = tid / 18,          g0 = tid % 18;
    const int r1 = (tid + 256) / 18,  g1 = (tid + 256) % 18;
    const int r2 = (tid + 512) / 18,  g2 = (tid + 512) % 18;
    const int r3 = (tid + 768) / 18,  g3 = (tid + 768) % 18;
    const int r4 = (tid + 1024) / 18, g4 = (tid + 1024) % 18;
    const int ko0 = r0 * DROW + g0 * 8, ko1 = r1 * DROW + g1 * 8;
    const int ko2 = r2 * DROW + g2 * 8, ko3 = r3 * DROW + g3 * 8;
    const int ko4 = r4 * DROW + g4 * 8;
    ushort_t* kld0 = &ksqs[r0][g0 * 8];
    ushort_t* kld1 = &ksqs[r1][g1 * 8];
    ushort_t* kld2 = &ksqs[r2][g2 * 8];
    ushort_t* kld3 = &ksqs[r3][g3 * 8];
    ushort_t* kld4 = &ksqs[r4][g4 * 8];
    const int rqa = tid / 18,          ga = tid % 18;
    const int rqb = (tid + 256) / 18,  gb = (tid + 256) % 18;
    const int voa = (rqa * 4) * DROW + ga * 8;
    const int vob = (rqb * 4) * DROW + gb * 8;
    const bool hasK4 = (tid < 128);
    const bool hasVB = (tid < 32);

    uint4 kp0, kp1, kp2, kp3, kp4;
    uint4 va0, va1, va2, va3, vb0, vb1, vb2, vb3;

#define LOAD_K(KC) do { \
        const __hip_bfloat16* kb_ = K + rowbase + (size_t)((KC) * 64) * DROW; \
        kp0 = *reinterpret_cast<const uint4*>(kb_ + ko0); \
        kp1 = *reinterpret_cast<const uint4*>(kb_ + ko1); \
        kp2 = *reinterpret_cast<const uint4*>(kb_ + ko2); \
        kp3 = *reinterpret_cast<const uint4*>(kb_ + ko3); \
        if (hasK4) kp4 = *reinterpret_cast<const uint4*>(kb_ + ko4); \
    } while (0)

#define LOAD_V(KC) do { \
        const __hip_bfloat16* vbp_ = V + rowbase + (size_t)((KC) * 64) * DROW; \
        va0 = *reinterpret_cast<const uint4*>(vbp_ + voa); \
        va1 = *reinterpret_cast<const uint4*>(vbp_ + voa + DROW); \
        va2 = *reinterpret_cast<const uint4*>(vbp_ + voa + 2 * DROW); \
        va3 = *reinterpret_cast<const uint4*>(vbp_ + voa + 3 * DROW); \
        if (hasVB) { \
            vb0 = *reinterpret_cast<const uint4*>(vbp_ + vob); \
            vb1 = *reinterpret_cast<const uint4*>(vbp_ + vob + DROW); \
            vb2 = *reinterpret_cast<const uint4*>(vbp_ + vob + 2 * DROW); \
            vb3 = *reinterpret_cast<const uint4*>(vbp_ + vob + 3 * DROW); \
        } \
    } while (0)

#define WRITE_KV() do { \
        *reinterpret_cast<uint4*>(kld0) = kp0; \
        *reinterpret_cast<uint4*>(kld1) = kp1; \
        *reinterpret_cast<uint4*>(kld2) = kp2; \
        *reinterpret_cast<uint4*>(kld3) = kp3; \
        if (hasK4) *reinterpret_cast<uint4*>(kld4) = kp4; \
        _Pragma("unroll") \
        for (int ii = 0; ii < 8; ++ii) { \
            uint2 pk; \
            pk.x = u16of(va0, ii) | (u16of(va1, ii) << 16); \
            pk.y = u16of(va2, ii) | (u16of(va3, ii) << 16); \
            *reinterpret_cast<uint2*>(&vst[ga * 8 + ii][rqa * 4]) = pk; \
        } \
        if (hasVB) { \
            _Pragma("unroll") \
            for (int ii = 0; ii < 8; ++ii) { \
                uint2 pk; \
                pk.x = u16of(vb0, ii) | (u16of(vb1, ii) << 16); \
                pk.y = u16of(vb2, ii) | (u16of(vb3, ii) << 16); \
                *reinterpret_cast<uint2*>(&vst[gb * 8 + ii][rqb * 4]) = pk; \
            } \
        } \
    } while (0)

    LOAD_K(0);
    LOAD_V(0);     // in flight across zero-init + whole Q phase

    for (int idx = tid; idx < 64 * 16; idx += 256)
        ksqs[idx >> 4][HD + (idx & 15)] = 0;
    for (int idx = tid; idx < 16 * VPAD2; idx += 256)
        vst[144 + idx / VPAD2][idx % VPAD2] = (idx / VPAD2 == 0) ? (ushort_t)0x3F80 : (ushort_t)0;

    bf16x8 aq[2][5];
    for (int hh = 0; hh < 2; ++hh) {
        __syncthreads();
        for (int idx = tid; idx < 64 * 18; idx += 256) {
            const int r = idx / 18, g = idx % 18;
            *reinterpret_cast<uint4*>(&ksqs[r][g * 8]) =
                *reinterpret_cast<const uint4*>(&Q[rowbase + (size_t)(q0 + hh * 64 + r) * DROW + g * 8]);
        }
        __syncthreads();
        if ((wave >> 1) == hh) {
            #pragma unroll
            for (int rt = 0; rt < 2; ++rt)
                #pragma unroll
                for (int kst = 0; kst < 5; ++kst)
                    aq[rt][kst] = *reinterpret_cast<const bf16x8*>(
                        &ksqs[32 * (wave & 1) + rt * 16 + l15][kst * 32 + quad * 8]);
        }
    }

    f32x4 oacc[2][10];
    #pragma unroll
    for (int rt = 0; rt < 2; ++rt)
        #pragma unroll
        for (int nt = 0; nt < 10; ++nt) oacc[rt][nt] = (f32x4){0.f, 0.f, 0.f, 0.f};

    for (int kc = 0; kc < 8; ++kc) {
        __syncthreads();          // aq reads / prev tile's LDS reads complete
        WRITE_KV();               // staged regs -> ksqs / vst
        __syncthreads();          // staging visible
        if (kc < 7) LOAD_K(kc + 1);   // K loads fly under QK^T MFMAs

        f32x4 sc[2][4];
        #pragma unroll
        for (int rt = 0; rt < 2; ++rt)
            #pragma unroll
            for (int kt = 0; kt < 4; ++kt) sc[rt][kt] = (f32x4){0.f, 0.f, 0.f, 0.f};
        #pragma unroll
        for (int kst = 0; kst < 5; ++kst) {
            bf16x8 bk[4];
            #pragma unroll
            for (int kt = 0; kt < 4; ++kt)
                bk[kt] = *reinterpret_cast<const bf16x8*>(
                    &ksqs[kt * 16 + l15][kst * 32 + quad * 8]);
            #pragma unroll
            for (int rt = 0; rt < 2; ++rt)
                #pragma unroll
                for (int kt = 0; kt < 4; ++kt)
                    sc[rt][kt] = __builtin_amdgcn_mfma_f32_16x16x32_bf16(aq[rt][kst], bk[kt], sc[rt][kt], 0, 0, 0);
        }

        if (kc < 7) LOAD_V(kc + 1);   // V loads fly under exp + PV phases

        #pragma unroll
        for (int rt = 0; rt < 2; ++rt)
            #pragma unroll
            for (int kt = 0; kt < 4; ++kt)
                #pragma unroll
                for (int i = 0; i < 4; ++i)
                    ps[32 * wave + 16 * rt + quad * 4 + i][16 * kt + l15] =
                        f2bu(exp2f(sc[rt][kt][i] * EXSCALE));

        #pragma unroll
        for (int kp = 0; kp < 2; ++kp) {
            bf16x8 pa[2];
            #pragma unroll
            for (int rt = 0; rt < 2; ++rt)
                pa[rt] = *reinterpret_cast<const bf16x8*>(
                    &ps[32 * wave + 16 * rt + l15][kp * 32 + quad * 8]);
            #pragma unroll
            for (int nt = 0; nt < 10; ++nt) {
                const bf16x8 bv = *reinterpret_cast<const bf16x8*>(
                    &vst[nt * 16 + l15][kp * 32 + quad * 8]);
                #pragma unroll
                for (int rt = 0; rt < 2; ++rt)
                    oacc[rt][nt] = __builtin_amdgcn_mfma_f32_16x16x32_bf16(pa[rt], bv, oacc[rt][nt], 0, 0, 0);
            }
        }
    }

    #pragma unroll
    for (int rt = 0; rt < 2; ++rt) {
        #pragma unroll
        for (int i = 0; i < 4; ++i) {
            const float l = __shfl(oacc[rt][9][i], lane & 48);
            const float inv = 1.0f / l;
            const int row = q0 + 32 * wave + 16 * rt + quad * 4 + i;
            const size_t rb = rowbase + (size_t)row * DROW;
            #pragma unroll
            for (int nt = 0; nt < 9; ++nt)
                O[rb + nt * 16 + l15] = __float2bfloat16(oacc[rt][nt][i] * inv);
        }
    }
#undef LOAD_K
#undef LOAD_V
#undef WRITE_KV
}

// ---------------------------------------------------------------------------
// Per-edge rotation matrix (faithful port of init_edge_rot_mat).
// ---------------------------------------------------------------------------
__global__ __launch_bounds__(256) void rot_kernel(
    const float* __restrict__ ev, const float* __restrict__ er,
    float* __restrict__ rot)
{
    const int e = blockIdx.x * 256 + threadIdx.x;
    if (e >= NEDGE) return;
    const float vx = ev[e * 3 + 0], vy = ev[e * 3 + 1], vz = ev[e * 3 + 2];
    const float d = sqrtf(vx * vx + vy * vy + vz * vz);
    const float nx0 = vx / d, nx1 = vy / d, nx2 = vz / d;
    float r0 = er[e * 3 + 0] - 0.5f;
    float r1 = er[e * 3 + 1] - 0.5f;
    float r2 = er[e * 3 + 2] - 0.5f;
    const float rn = sqrtf(r0 * r0 + r1 * r1 + r2 * r2);
    r0 /= rn; r1 /= rn; r2 /= rn;
    const float b0 = -r1, b1 = r0, b2v = r2;          // e2b
    const float c0 = r0, c1 = -r2, c2 = r1;           // e2c
    const float vd0 = fabsf(r0 * nx0 + r1 * nx1 + r2 * nx2);
    const float vdb = fabsf(b0 * nx0 + b1 * nx1 + b2v * nx2);
    const float vdc = fabsf(c0 * nx0 + c1 * nx1 + c2 * nx2);
    if (vd0 > vdb) { r0 = b0; r1 = b1; r2 = b2v; }
    const float vd1 = fabsf(r0 * nx0 + r1 * nx1 + r2 * nx2);
    if (vd1 > vdc) { r0 = c0; r1 = c1; r2 = c2; }
    float z0 = nx1 * r2 - nx2 * r1;
    float z1 = nx2 * r0 - nx0 * r2;
    float z2 = nx0 * r1 - nx1 * r0;
    const float zn = sqrtf(z0 * z0 + z1 * z1 + z2 * z2);
    z0 /= zn; z1 /= zn; z2 /= zn;
    float y0 = nx1 * z2 - nx2 * z1;
    float y1 = nx2 * z0 - nx0 * z2;
    float y2 = nx0 * z1 - nx1 * z0;
    const float yn = sqrtf(y0 * y0 + y1 * y1 + y2 * y2);
    y0 /= yn; y1 /= yn; y2 /= yn;
    float* rp = rot + (size_t)e * 9;
    rp[0] = z0;   rp[1] = z1;   rp[2] = z2;
    rp[3] = nx0;  rp[4] = nx1;  rp[5] = nx2;
    rp[6] = -y0;  rp[7] = -y1;  rp[8] = -y2;
}

extern "C" void kernel_launch(void* const* d_in, const int* in_sizes, int n_in,
                              void* d_out, int out_size, void* d_ws, size_t ws_size,
                              hipStream_t stream)
{
    (void)in_sizes; (void)n_in; (void)out_size; (void)ws_size;
    const float* x     = (const float*)d_in[0];
    const float* ev    = (const float*)d_in[1];
    const float* er    = (const float*)d_in[2];
    const float* Wq    = (const float*)d_in[3];
    const float* Wk    = (const float*)d_in[4];
    const float* Wv    = (const float*)d_in[5];
    const float* Wo    = (const float*)d_in[6];
    const float* gamma = (const float*)d_in[7];
    const float* beta  = (const float*)d_in[8];
    // d_in[9] edge_index, d_in[10] batch: unused by the reference math.

    float* out = (float*)d_out;
    float* rot = out + (size_t)NNODE * DROW;

    const size_t ND = (size_t)NNODE * DROW;
    __hip_bfloat16* q = (__hip_bfloat16*)d_ws;   // 4 x N*D bf16 = 75.5 MB scratch
    __hip_bfloat16* k = q + ND;
    __hip_bfloat16* v = k + ND;
    __hip_bfloat16* o = v + ND;

    rot_kernel<<<NEDGE / 256, 256, 0, stream>>>(ev, er, rot);

    // fused q/k/v linears: all l-levels in one kernel, X read once
    qkv_fused<<<NNODE / 16, 256, 0, stream>>>(x, Wq, Wk, Wv, q, k, v);

    attn_kernel<<<(MSEQ / 128) * NHEAD * BATCH, 256, 0, stream>>>(q, k, v, o);

    // output linear + residual; l0 fuses LayerNorm+SiLU (writes out[:, :128])
    lin_mfma<1, 64, 1, 1, __hip_bfloat16, float><<<NNODE / 64, 256, 0, stream>>>(
        o, Wo, nullptr, nullptr, out, nullptr, nullptr, x, gamma, beta, 0);
    lin_mfma<3, 32, 1, 0, __hip_bfloat16, float><<<NNODE / 32, 256, 0, stream>>>(
        o, Wo + 16384, nullptr, nullptr, out, nullptr, nullptr, x, nullptr, nullptr, 128);
    lin_mfma<5, 16, 1, 0, __hip_bfloat16, float><<<NNODE / 16, 256, 0, stream>>>(
        o, Wo + 32768, nullptr, nullptr, out, nullptr, nullptr, x, nullptr, nullptr, 512);
}

// Round 8
// 244.460 us; speedup vs baseline: 1.0273x; 1.0273x over previous
//
#include <hip/hip_runtime.h>
#include <hip/hip_bf16.h>

// Problem constants (from reference)
#define C_CH   128
#define DROW   1152          // C * (1+3+5)
#define NNODE  8192          // B*M
#define BATCH  16
#define MSEQ   512
#define NHEAD  8
#define HD     144           // DROW / NHEAD
#define NEDGE  262144

typedef unsigned short ushort_t;
typedef __attribute__((ext_vector_type(8))) short bf16x8;
typedef __attribute__((ext_vector_type(4))) float f32x4;

__device__ __forceinline__ ushort_t f2bu(float x) {
    __hip_bfloat16 h = __float2bfloat16(x);
    return *reinterpret_cast<ushort_t*>(&h);
}
__device__ __forceinline__ float bu2f(ushort_t u) {
    return __bfloat162float(*reinterpret_cast<__hip_bfloat16*>(&u));
}
// static-index halfword extract from a uint4 held in registers (no memory)
__device__ __forceinline__ unsigned u16of(const uint4 v, int ii) {
    const unsigned w = ((ii >> 1) == 0) ? v.x : ((ii >> 1) == 1) ? v.y :
                       ((ii >> 1) == 2) ? v.z : v.w;
    return (ii & 1) ? (w >> 16) : (w & 0xFFFFu);
}

#define KP2 136   // LDS row elems for K=128 (+8 pad)

// ---------------------------------------------------------------------------
// NZ=1 irreps_linear with LDS OVERLAY: Es reuses Xs's storage (Xs dead after
// GEMM; extra barrier separates last Xs read from first Es write). LDS
// halves => 6-8 blocks/CU instead of 2-3 (these kernels are latency-bound
// against an L3-resident working set — R7 lesson). Per-element math is
// round-0 verbatim => bitwise-identical. QKV: TY=bf16, z = blockIdx.y picks
// {Wq,Wk,Wv}. OUT l1/l2: TY=float, resid add, grid.y=1.
// ---------------------------------------------------------------------------
template<int DL, int NPB, typename TX, typename TY>
__global__ __launch_bounds__(256) void lin_ovl(
    const TX* __restrict__ X,
    const float* __restrict__ W0, const float* __restrict__ W1,
    const float* __restrict__ W2,
    TY* __restrict__ Y0, TY* __restrict__ Y1, TY* __restrict__ Y2,
    const float* __restrict__ resid,
    int baseoff)
{
    constexpr int COLS = NPB * DL;     // GEMM columns per block (multiple of 16)
    constexpr int CT   = COLS / 16;
    __shared__ __align__(16) ushort_t Bs[COLS][KP2];   // Xs, then Es (overlay)

    const int tid  = threadIdx.x;
    const int wave = tid >> 6;
    const int lane = tid & 63;
    const int l15  = lane & 15;
    const int quad = lane >> 4;
    const int n0   = blockIdx.x * NPB;
    const int z    = blockIdx.y;

    const float* W = (z == 0) ? W0 : (z == 1 ? W1 : W2);
    TY* Y          = (z == 0) ? Y0 : (z == 1 ? Y1 : Y2);

    // ---- stage X^T: Bs[nb*DL + m][c] = X[n0+nb, baseoff + c*DL + m] ----
    if constexpr (sizeof(TX) == 4) {
        for (int e4 = tid; e4 < NPB * 32 * DL; e4 += 256) {
            const int nb = e4 / (32 * DL);
            const int rr = (e4 - nb * (32 * DL)) * 4;
            const float4 xv = *reinterpret_cast<const float4*>(
                &X[(size_t)(n0 + nb) * DROW + baseoff + rr]);
            #pragma unroll
            for (int j = 0; j < 4; ++j) {
                const int r = rr + j, c = r / DL, m = r - c * DL;
                Bs[nb * DL + m][c] = f2bu(reinterpret_cast<const float*>(&xv)[j]);
            }
        }
    } else {
        for (int e8 = tid; e8 < NPB * 16 * DL; e8 += 256) {
            const int nb = e8 / (16 * DL);
            const int rr = (e8 - nb * (16 * DL)) * 8;
            const uint4 xv = *reinterpret_cast<const uint4*>(
                &X[(size_t)(n0 + nb) * DROW + baseoff + rr]);
            const ushort_t* xs = reinterpret_cast<const ushort_t*>(&xv);
            #pragma unroll
            for (int j = 0; j < 8; ++j) {
                const int r = rr + j, c = r / DL, m = r - c * DL;
                Bs[nb * DL + m][c] = xs[j];
            }
        }
    }

    const float s = 0.08838834764831845f;      // 1/sqrt(128)

    // W fragments -> registers (wave owns o in [32w, 32w+32))
    bf16x8 aw[2][4];
    #pragma unroll
    for (int ot = 0; ot < 2; ++ot)
        #pragma unroll
        for (int kst = 0; kst < 4; ++kst) {
            const float* wp = &W[(size_t)(32 * wave + 16 * ot + l15) * 128 + kst * 32 + quad * 8];
            const float4 wa = *reinterpret_cast<const float4*>(wp);
            const float4 wb = *reinterpret_cast<const float4*>(wp + 4);
            ushort_t t[8] = {f2bu(wa.x), f2bu(wa.y), f2bu(wa.z), f2bu(wa.w),
                             f2bu(wb.x), f2bu(wb.y), f2bu(wb.z), f2bu(wb.w)};
            aw[ot][kst] = *reinterpret_cast<const bf16x8*>(t);
        }

    __syncthreads();   // Xs staged

    f32x4 acc[CT][2];
    #pragma unroll
    for (int ct = 0; ct < CT; ++ct) {
        acc[ct][0] = (f32x4){0.f, 0.f, 0.f, 0.f};
        acc[ct][1] = (f32x4){0.f, 0.f, 0.f, 0.f};
    }
    #pragma unroll
    for (int kst = 0; kst < 4; ++kst)
        #pragma unroll
        for (int ct = 0; ct < CT; ++ct) {
            const bf16x8 b = *reinterpret_cast<const bf16x8*>(
                &Bs[ct * 16 + l15][kst * 32 + quad * 8]);
            acc[ct][0] = __builtin_amdgcn_mfma_f32_16x16x32_bf16(aw[0][kst], b, acc[ct][0], 0, 0, 0);
            acc[ct][1] = __builtin_amdgcn_mfma_f32_16x16x32_bf16(aw[1][kst], b, acc[ct][1], 0, 0, 0);
        }

    __syncthreads();   // ALL waves done reading Xs (overlay hazard barrier)

    // C -> Es[col][o] (scale applied here), Es overlaid on Xs storage
    #pragma unroll
    for (int ct = 0; ct < CT; ++ct)
        #pragma unroll
        for (int ot = 0; ot < 2; ++ot) {
            ushort_t t[4] = {f2bu(acc[ct][ot][0] * s), f2bu(acc[ct][ot][1] * s),
                             f2bu(acc[ct][ot][2] * s), f2bu(acc[ct][ot][3] * s)};
            *reinterpret_cast<uint2*>(&Bs[ct * 16 + l15][32 * wave + 16 * ot + quad * 4]) =
                *reinterpret_cast<const uint2*>(t);
        }
    __syncthreads();   // Es visible

    // coalesced store: contiguous spans of 8 output elems r = o*DL+m
    for (int e8 = tid; e8 < COLS * 16; e8 += 256) {
        const int nb = e8 / (16 * DL);
        const int r0 = (e8 - nb * (16 * DL)) * 8;
        const size_t ga = (size_t)(n0 + nb) * DROW + baseoff + r0;
        if constexpr (sizeof(TY) == 2) {
            ushort_t t[8];
            #pragma unroll
            for (int j = 0; j < 8; ++j) {
                const int r = r0 + j;
                t[j] = Bs[nb * DL + r % DL][r / DL];
            }
            *reinterpret_cast<uint4*>(&Y[ga]) = *reinterpret_cast<const uint4*>(t);
        } else {
            #pragma unroll
            for (int j4 = 0; j4 < 2; ++j4) {
                const float4 rv = *reinterpret_cast<const float4*>(&resid[ga + j4 * 4]);
                float4 ov;
                #pragma unroll
                for (int j = 0; j < 4; ++j) {
                    const int r = r0 + j4 * 4 + j;
                    reinterpret_cast<float*>(&ov)[j] =
                        bu2f(Bs[nb * DL + r % DL][r / DL]) +
                        reinterpret_cast<const float*>(&rv)[j];
                }
                *reinterpret_cast<float4*>(&((float*)Y)[ga + j4 * 4]) = ov;
            }
        }
    }
}

// ---------------------------------------------------------------------------
// irreps_linear — ROUND-0 VERBATIM. Used ONLY for the out-l0 LN kernel
// (the LN epilogue is never touched — R1/R2 regression lived in this region).
// ---------------------------------------------------------------------------
template<int DL, int NPB, int NZ, int FUSE_LN, typename TX, typename TY>
__global__ __launch_bounds__(256) void lin_mfma(
    const TX* __restrict__ X,
    const float* __restrict__ W0, const float* __restrict__ W1,
    const float* __restrict__ W2,
    TY* __restrict__ Y0, TY* __restrict__ Y1, TY* __restrict__ Y2,
    const float* __restrict__ resid,
    const float* __restrict__ gamma, const float* __restrict__ beta,
    int baseoff)
{
    constexpr int COLS = NPB * DL;     // GEMM columns per block (multiple of 16)
    constexpr int CT   = COLS / 16;
    __shared__ __align__(16) ushort_t Xs[COLS][KP2];
    __shared__ __align__(16) ushort_t Es[COLS][KP2];

    const int tid  = threadIdx.x;
    const int wave = tid >> 6;
    const int lane = tid & 63;
    const int l15  = lane & 15;
    const int quad = lane >> 4;
    const int n0   = blockIdx.x * NPB;

    // ---- stage X^T: Xs[nb*DL + m][c] = X[n0+nb, baseoff + c*DL + m] ----
    if constexpr (sizeof(TX) == 4) {
        for (int e4 = tid; e4 < NPB * 32 * DL; e4 += 256) {
            const int nb = e4 / (32 * DL);
            const int rr = (e4 - nb * (32 * DL)) * 4;
            const float4 xv = *reinterpret_cast<const float4*>(
                &X[(size_t)(n0 + nb) * DROW + baseoff + rr]);
            #pragma unroll
            for (int j = 0; j < 4; ++j) {
                const int r = rr + j, c = r / DL, m = r - c * DL;
                Xs[nb * DL + m][c] = f2bu(reinterpret_cast<const float*>(&xv)[j]);
            }
        }
    } else {
        for (int e8 = tid; e8 < NPB * 16 * DL; e8 += 256) {
            const int nb = e8 / (16 * DL);
            const int rr = (e8 - nb * (16 * DL)) * 8;
            const uint4 xv = *reinterpret_cast<const uint4*>(
                &X[(size_t)(n0 + nb) * DROW + baseoff + rr]);
            const ushort_t* xs = reinterpret_cast<const ushort_t*>(&xv);
            #pragma unroll
            for (int j = 0; j < 8; ++j) {
                const int r = rr + j, c = r / DL, m = r - c * DL;
                Xs[nb * DL + m][c] = xs[j];
            }
        }
    }

    const float s = 0.08838834764831845f;      // 1/sqrt(128)

    for (int z = 0; z < NZ; ++z) {
        const float* W = (z == 0) ? W0 : (z == 1 ? W1 : W2);
        TY* Y          = (z == 0) ? Y0 : (z == 1 ? Y1 : Y2);

        // W fragments -> registers (wave owns o in [32w, 32w+32))
        bf16x8 aw[2][4];
        #pragma unroll
        for (int ot = 0; ot < 2; ++ot)
            #pragma unroll
            for (int kst = 0; kst < 4; ++kst) {
                const float* wp = &W[(size_t)(32 * wave + 16 * ot + l15) * 128 + kst * 32 + quad * 8];
                const float4 wa = *reinterpret_cast<const float4*>(wp);
                const float4 wb = *reinterpret_cast<const float4*>(wp + 4);
                ushort_t t[8] = {f2bu(wa.x), f2bu(wa.y), f2bu(wa.z), f2bu(wa.w),
                                 f2bu(wb.x), f2bu(wb.y), f2bu(wb.z), f2bu(wb.w)};
                aw[ot][kst] = *reinterpret_cast<const bf16x8*>(t);
            }

        __syncthreads();   // Xs staged (z=0); prev z's Es reads done (z>0)

        f32x4 acc[CT][2];
        #pragma unroll
        for (int ct = 0; ct < CT; ++ct) {
            acc[ct][0] = (f32x4){0.f, 0.f, 0.f, 0.f};
            acc[ct][1] = (f32x4){0.f, 0.f, 0.f, 0.f};
        }
        #pragma unroll
        for (int kst = 0; kst < 4; ++kst)
            #pragma unroll
            for (int ct = 0; ct < CT; ++ct) {
                const bf16x8 b = *reinterpret_cast<const bf16x8*>(
                    &Xs[ct * 16 + l15][kst * 32 + quad * 8]);
                acc[ct][0] = __builtin_amdgcn_mfma_f32_16x16x32_bf16(aw[0][kst], b, acc[ct][0], 0, 0, 0);
                acc[ct][1] = __builtin_amdgcn_mfma_f32_16x16x32_bf16(aw[1][kst], b, acc[ct][1], 0, 0, 0);
            }

        // C -> Es[col][o] (scale applied here)
        #pragma unroll
        for (int ct = 0; ct < CT; ++ct)
            #pragma unroll
            for (int ot = 0; ot < 2; ++ot) {
                ushort_t t[4] = {f2bu(acc[ct][ot][0] * s), f2bu(acc[ct][ot][1] * s),
                                 f2bu(acc[ct][ot][2] * s), f2bu(acc[ct][ot][3] * s)};
                *reinterpret_cast<uint2*>(&Es[ct * 16 + l15][32 * wave + 16 * ot + quad * 4]) =
                    *reinterpret_cast<const uint2*>(t);
            }
        __syncthreads();

        if constexpr (FUSE_LN) {
            // DL==1, NPB==64: 4 lanes per node, 32 channels each
            const int nb = tid >> 2, cc = tid & 3;
            float y[32];
            const float* xr = resid + (size_t)(n0 + nb) * DROW + cc * 32;
            float s1 = 0.f, s2 = 0.f;
            #pragma unroll
            for (int j4 = 0; j4 < 8; ++j4) {
                const float4 rv = *reinterpret_cast<const float4*>(xr + j4 * 4);
                #pragma unroll
                for (int j = 0; j < 4; ++j) {
                    const float v = bu2f(Es[nb][cc * 32 + j4 * 4 + j]) +
                                    reinterpret_cast<const float*>(&rv)[j];
                    y[j4 * 4 + j] = v; s1 += v; s2 += v * v;
                }
            }
            s1 += __shfl_xor(s1, 1); s2 += __shfl_xor(s2, 1);
            s1 += __shfl_xor(s1, 2); s2 += __shfl_xor(s2, 2);
            const float mean = s1 * (1.0f / 128.0f);
            const float var  = s2 * (1.0f / 128.0f) - mean * mean;
            const float rstd = rsqrtf(var + 1e-5f);
            float* op = (float*)Y + (size_t)(n0 + nb) * DROW + cc * 32;
            #pragma unroll
            for (int j4 = 0; j4 < 8; ++j4) {
                float4 ov;
                #pragma unroll
                for (int j = 0; j < 4; ++j) {
                    const int c = cc * 32 + j4 * 4 + j;
                    float t = (y[j4 * 4 + j] - mean) * rstd * gamma[c] + beta[c];
                    reinterpret_cast<float*>(&ov)[j] = t / (1.0f + __expf(-t));
                }
                *reinterpret_cast<float4*>(op + j4 * 4) = ov;
            }
        } else {
            // coalesced store: contiguous spans of 8 output elems r = o*DL+m
            for (int e8 = tid; e8 < COLS * 16; e8 += 256) {
                const int nb = e8 / (16 * DL);
                const int r0 = (e8 - nb * (16 * DL)) * 8;
                const size_t ga = (size_t)(n0 + nb) * DROW + baseoff + r0;
                if constexpr (sizeof(TY) == 2) {
                    ushort_t t[8];
                    #pragma unroll
                    for (int j = 0; j < 8; ++j) {
                        const int r = r0 + j;
                        t[j] = Es[nb * DL + r % DL][r / DL];
                    }
                    *reinterpret_cast<uint4*>(&Y[ga]) = *reinterpret_cast<const uint4*>(t);
                } else {
                    #pragma unroll
                    for (int j4 = 0; j4 < 2; ++j4) {
                        const float4 rv = *reinterpret_cast<const float4*>(&resid[ga + j4 * 4]);
                        float4 ov;
                        #pragma unroll
                        for (int j = 0; j < 4; ++j) {
                            const int r = r0 + j4 * 4 + j;
                            reinterpret_cast<float*>(&ov)[j] =
                                bu2f(Es[nb * DL + r % DL][r / DL]) +
                                reinterpret_cast<const float*>(&rv)[j];
                        }
                        *reinterpret_cast<float4*>(&((float*)Y)[ga + j4 * 4]) = ov;
                    }
                }
            }
        }
    }
}

// ---------------------------------------------------------------------------
// One-pass MFMA attention — ROUND-5 VERBATIM (T14 register-true prefetch).
// ---------------------------------------------------------------------------
#define KPAD  168   // ksqs row elems (144 data + 16 zero-pad + 8)
#define VROWS 160   // 144 V-cols + ones-row + 15 zero rows
#define VPAD2 72    // vst row elems (64 keys + 8)
#define PPAD  68    // ps row elems (64 keys + 4)

__global__ __launch_bounds__(256, 2) void attn_kernel(
    const __hip_bfloat16* __restrict__ Q, const __hip_bfloat16* __restrict__ K,
    const __hip_bfloat16* __restrict__ V, __hip_bfloat16* __restrict__ O)
{
    __shared__ __align__(16) ushort_t ksqs[64][KPAD];   // 21504 B
    __shared__ __align__(16) ushort_t vst[VROWS][VPAD2];// 23040 B
    __shared__ __align__(16) ushort_t ps[128][PPAD];    // 17408 B

    const int tid  = threadIdx.x;
    const int wave = tid >> 6;
    const int lane = tid & 63;
    const int l15  = lane & 15;
    const int quad = lane >> 4;

    const int bid = blockIdx.x;
    const int xcd = bid & 7;
    const int j   = bid >> 3;              // 0..63
    const int bh  = xcd * 16 + (j >> 2);   // 0..127
    const int q0  = (j & 3) * 128;
    const int h   = bh & 7;
    const int b   = bh >> 3;
    const size_t rowbase = (size_t)b * MSEQ * DROW + (size_t)h * HD;
    const float EXSCALE = 0.12022458674074695f;   // log2(e)/sqrt(144)

    // ---- per-thread staging geometry (computed once) ----
    const int r0 = tid / 18,          g0 = tid % 18;
    const int r1 = (tid + 256) / 18,  g1 = (tid + 256) % 18;
    const int r2 = (tid + 512) / 18,  g2 = (tid + 512) % 18;
    const int r3 = (tid + 768) / 18,  g3 = (tid + 768) % 18;
    const int r4 = (tid + 1024) / 18, g4 = (tid + 1024) % 18;
    const int ko0 = r0 * DROW + g0 * 8, ko1 = r1 * DROW + g1 * 8;
    const int ko2 = r2 * DROW + g2 * 8, ko3 = r3 * DROW + g3 * 8;
    const int ko4 = r4 * DROW + g4 * 8;
    ushort_t* kld0 = &ksqs[r0][g0 * 8];
    ushort_t* kld1 = &ksqs[r1][g1 * 8];
    ushort_t* kld2 = &ksqs[r2][g2 * 8];
    ushort_t* kld3 = &ksqs[r3][g3 * 8];
    ushort_t* kld4 = &ksqs[r4][g4 * 8];
    const int rqa = tid / 18,          ga = tid % 18;
    const int rqb = (tid + 256) / 18,  gb = (tid + 256) % 18;
    const int voa = (rqa * 4) * DROW + ga * 8;
    const int vob = (rqb * 4) * DROW + gb * 8;
    const bool hasK4 = (tid < 128);
    const bool hasVB = (tid < 32);

    uint4 kp0, kp1, kp2, kp3, kp4;
    uint4 va0, va1, va2, va3, vb0, vb1, vb2, vb3;

#define LOAD_K(KC) do { \
        const __hip_bfloat16* kb_ = K + rowbase + (size_t)((KC) * 64) * DROW; \
        kp0 = *reinterpret_cast<const uint4*>(kb_ + ko0); \
        kp1 = *reinterpret_cast<const uint4*>(kb_ + ko1); \
        kp2 = *reinterpret_cast<const uint4*>(kb_ + ko2); \
        kp3 = *reinterpret_cast<const uint4*>(kb_ + ko3); \
        if (hasK4) kp4 = *reinterpret_cast<const uint4*>(kb_ + ko4); \
    } while (0)

#define LOAD_V(KC) do { \
        const __hip_bfloat16* vbp_ = V + rowbase + (size_t)((KC) * 64) * DROW; \
        va0 = *reinterpret_cast<const uint4*>(vbp_ + voa); \
        va1 = *reinterpret_cast<const uint4*>(vbp_ + voa + DROW); \
        va2 = *reinterpret_cast<const uint4*>(vbp_ + voa + 2 * DROW); \
        va3 = *reinterpret_cast<const uint4*>(vbp_ + voa + 3 * DROW); \
        if (hasVB) { \
            vb0 = *reinterpret_cast<const uint4*>(vbp_ + vob); \
            vb1 = *reinterpret_cast<const uint4*>(vbp_ + vob + DROW); \
            vb2 = *reinterpret_cast<const uint4*>(vbp_ + vob + 2 * DROW); \
            vb3 = *reinterpret_cast<const uint4*>(vbp_ + vob + 3 * DROW); \
        } \
    } while (0)

#define WRITE_KV() do { \
        *reinterpret_cast<uint4*>(kld0) = kp0; \
        *reinterpret_cast<uint4*>(kld1) = kp1; \
        *reinterpret_cast<uint4*>(kld2) = kp2; \
        *reinterpret_cast<uint4*>(kld3) = kp3; \
        if (hasK4) *reinterpret_cast<uint4*>(kld4) = kp4; \
        _Pragma("unroll") \
        for (int ii = 0; ii < 8; ++ii) { \
            uint2 pk; \
            pk.x = u16of(va0, ii) | (u16of(va1, ii) << 16); \
            pk.y = u16of(va2, ii) | (u16of(va3, ii) << 16); \
            *reinterpret_cast<uint2*>(&vst[ga * 8 + ii][rqa * 4]) = pk; \
        } \
        if (hasVB) { \
            _Pragma("unroll") \
            for (int ii = 0; ii < 8; ++ii) { \
                uint2 pk; \
                pk.x = u16of(vb0, ii) | (u16of(vb1, ii) << 16); \
                pk.y = u16of(vb2, ii) | (u16of(vb3, ii) << 16); \
                *reinterpret_cast<uint2*>(&vst[gb * 8 + ii][rqb * 4]) = pk; \
            } \
        } \
    } while (0)

    LOAD_K(0);
    LOAD_V(0);     // in flight across zero-init + whole Q phase

    for (int idx = tid; idx < 64 * 16; idx += 256)
        ksqs[idx >> 4][HD + (idx & 15)] = 0;
    for (int idx = tid; idx < 16 * VPAD2; idx += 256)
        vst[144 + idx / VPAD2][idx % VPAD2] = (idx / VPAD2 == 0) ? (ushort_t)0x3F80 : (ushort_t)0;

    bf16x8 aq[2][5];
    for (int hh = 0; hh < 2; ++hh) {
        __syncthreads();
        for (int idx = tid; idx < 64 * 18; idx += 256) {
            const int r = idx / 18, g = idx % 18;
            *reinterpret_cast<uint4*>(&ksqs[r][g * 8]) =
                *reinterpret_cast<const uint4*>(&Q[rowbase + (size_t)(q0 + hh * 64 + r) * DROW + g * 8]);
        }
        __syncthreads();
        if ((wave >> 1) == hh) {
            #pragma unroll
            for (int rt = 0; rt < 2; ++rt)
                #pragma unroll
                for (int kst = 0; kst < 5; ++kst)
                    aq[rt][kst] = *reinterpret_cast<const bf16x8*>(
                        &ksqs[32 * (wave & 1) + rt * 16 + l15][kst * 32 + quad * 8]);
        }
    }

    f32x4 oacc[2][10];
    #pragma unroll
    for (int rt = 0; rt < 2; ++rt)
        #pragma unroll
        for (int nt = 0; nt < 10; ++nt) oacc[rt][nt] = (f32x4){0.f, 0.f, 0.f, 0.f};

    for (int kc = 0; kc < 8; ++kc) {
        __syncthreads();          // aq reads / prev tile's LDS reads complete
        WRITE_KV();               // staged regs -> ksqs / vst
        __syncthreads();          // staging visible
        if (kc < 7) LOAD_K(kc + 1);   // K loads fly under QK^T MFMAs

        f32x4 sc[2][4];
        #pragma unroll
        for (int rt = 0; rt < 2; ++rt)
            #pragma unroll
            for (int kt = 0; kt < 4; ++kt) sc[rt][kt] = (f32x4){0.f, 0.f, 0.f, 0.f};
        #pragma unroll
        for (int kst = 0; kst < 5; ++kst) {
            bf16x8 bk[4];
            #pragma unroll
            for (int kt = 0; kt < 4; ++kt)
                bk[kt] = *reinterpret_cast<const bf16x8*>(
                    &ksqs[kt * 16 + l15][kst * 32 + quad * 8]);
            #pragma unroll
            for (int rt = 0; rt < 2; ++rt)
                #pragma unroll
                for (int kt = 0; kt < 4; ++kt)
                    sc[rt][kt] = __builtin_amdgcn_mfma_f32_16x16x32_bf16(aq[rt][kst], bk[kt], sc[rt][kt], 0, 0, 0);
        }

        if (kc < 7) LOAD_V(kc + 1);   // V loads fly under exp + PV phases

        #pragma unroll
        for (int rt = 0; rt < 2; ++rt)
            #pragma unroll
            for (int kt = 0; kt < 4; ++kt)
                #pragma unroll
                for (int i = 0; i < 4; ++i)
                    ps[32 * wave + 16 * rt + quad * 4 + i][16 * kt + l15] =
                        f2bu(exp2f(sc[rt][kt][i] * EXSCALE));

        #pragma unroll
        for (int kp = 0; kp < 2; ++kp) {
            bf16x8 pa[2];
            #pragma unroll
            for (int rt = 0; rt < 2; ++rt)
                pa[rt] = *reinterpret_cast<const bf16x8*>(
                    &ps[32 * wave + 16 * rt + l15][kp * 32 + quad * 8]);
            #pragma unroll
            for (int nt = 0; nt < 10; ++nt) {
                const bf16x8 bv = *reinterpret_cast<const bf16x8*>(
                    &vst[nt * 16 + l15][kp * 32 + quad * 8]);
                #pragma unroll
                for (int rt = 0; rt < 2; ++rt)
                    oacc[rt][nt] = __builtin_amdgcn_mfma_f32_16x16x32_bf16(pa[rt], bv, oacc[rt][nt], 0, 0, 0);
            }
        }
    }

    #pragma unroll
    for (int rt = 0; rt < 2; ++rt) {
        #pragma unroll
        for (int i = 0; i < 4; ++i) {
            const float l = __shfl(oacc[rt][9][i], lane & 48);
            const float inv = 1.0f / l;
            const int row = q0 + 32 * wave + 16 * rt + quad * 4 + i;
            const size_t rb = rowbase + (size_t)row * DROW;
            #pragma unroll
            for (int nt = 0; nt < 9; ++nt)
                O[rb + nt * 16 + l15] = __float2bfloat16(oacc[rt][nt][i] * inv);
        }
    }
#undef LOAD_K
#undef LOAD_V
#undef WRITE_KV
}

// ---------------------------------------------------------------------------
// Per-edge rotation matrix (faithful port of init_edge_rot_mat).
// ---------------------------------------------------------------------------
__global__ __launch_bounds__(256) void rot_kernel(
    const float* __restrict__ ev, const float* __restrict__ er,
    float* __restrict__ rot)
{
    const int e = blockIdx.x * 256 + threadIdx.x;
    if (e >= NEDGE) return;
    const float vx = ev[e * 3 + 0], vy = ev[e * 3 + 1], vz = ev[e * 3 + 2];
    const float d = sqrtf(vx * vx + vy * vy + vz * vz);
    const float nx0 = vx / d, nx1 = vy / d, nx2 = vz / d;
    float r0 = er[e * 3 + 0] - 0.5f;
    float r1 = er[e * 3 + 1] - 0.5f;
    float r2 = er[e * 3 + 2] - 0.5f;
    const float rn = sqrtf(r0 * r0 + r1 * r1 + r2 * r2);
    r0 /= rn; r1 /= rn; r2 /= rn;
    const float b0 = -r1, b1 = r0, b2v = r2;          // e2b
    const float c0 = r0, c1 = -r2, c2 = r1;           // e2c
    const float vd0 = fabsf(r0 * nx0 + r1 * nx1 + r2 * nx2);
    const float vdb = fabsf(b0 * nx0 + b1 * nx1 + b2v * nx2);
    const float vdc = fabsf(c0 * nx0 + c1 * nx1 + c2 * nx2);
    if (vd0 > vdb) { r0 = b0; r1 = b1; r2 = b2v; }
    const float vd1 = fabsf(r0 * nx0 + r1 * nx1 + r2 * nx2);
    if (vd1 > vdc) { r0 = c0; r1 = c1; r2 = c2; }
    float z0 = nx1 * r2 - nx2 * r1;
    float z1 = nx2 * r0 - nx0 * r2;
    float z2 = nx0 * r1 - nx1 * r0;
    const float zn = sqrtf(z0 * z0 + z1 * z1 + z2 * z2);
    z0 /= zn; z1 /= zn; z2 /= zn;
    float y0 = nx1 * z2 - nx2 * z1;
    float y1 = nx2 * z0 - nx0 * z2;
    float y2 = nx0 * z1 - nx1 * z0;
    const float yn = sqrtf(y0 * y0 + y1 * y1 + y2 * y2);
    y0 /= yn; y1 /= yn; y2 /= yn;
    float* rp = rot + (size_t)e * 9;
    rp[0] = z0;   rp[1] = z1;   rp[2] = z2;
    rp[3] = nx0;  rp[4] = nx1;  rp[5] = nx2;
    rp[6] = -y0;  rp[7] = -y1;  rp[8] = -y2;
}

extern "C" void kernel_launch(void* const* d_in, const int* in_sizes, int n_in,
                              void* d_out, int out_size, void* d_ws, size_t ws_size,
                              hipStream_t stream)
{
    (void)in_sizes; (void)n_in; (void)out_size; (void)ws_size;
    const float* x     = (const float*)d_in[0];
    const float* ev    = (const float*)d_in[1];
    const float* er    = (const float*)d_in[2];
    const float* Wq    = (const float*)d_in[3];
    const float* Wk    = (const float*)d_in[4];
    const float* Wv    = (const float*)d_in[5];
    const float* Wo    = (const float*)d_in[6];
    const float* gamma = (const float*)d_in[7];
    const float* beta  = (const float*)d_in[8];
    // d_in[9] edge_index, d_in[10] batch: unused by the reference math.

    float* out = (float*)d_out;
    float* rot = out + (size_t)NNODE * DROW;

    const size_t ND = (size_t)NNODE * DROW;
    __hip_bfloat16* q = (__hip_bfloat16*)d_ws;   // 4 x N*D bf16 = 75.5 MB scratch
    __hip_bfloat16* k = q + ND;
    __hip_bfloat16* v = k + ND;
    __hip_bfloat16* o = v + ND;

    rot_kernel<<<NEDGE / 256, 256, 0, stream>>>(ev, er, rot);

    // q/k/v linears: z in grid (R6) + LDS overlay + smaller NPB for more
    // blocks in flight (768 / 1536 / 1536 blocks, 6-8 blocks/CU)
    lin_ovl<1, 32, float, __hip_bfloat16><<<dim3(NNODE / 32, 3), 256, 0, stream>>>(
        x, Wq, Wk, Wv, q, k, v, nullptr, 0);
    lin_ovl<3, 16, float, __hip_bfloat16><<<dim3(NNODE / 16, 3), 256, 0, stream>>>(
        x, Wq + 16384, Wk + 16384, Wv + 16384, q, k, v, nullptr, 128);
    lin_ovl<5, 16, float, __hip_bfloat16><<<dim3(NNODE / 16, 3), 256, 0, stream>>>(
        x, Wq + 32768, Wk + 32768, Wv + 32768, q, k, v, nullptr, 512);

    attn_kernel<<<(MSEQ / 128) * NHEAD * BATCH, 256, 0, stream>>>(q, k, v, o);

    // output linear + residual; l0 fuses LayerNorm+SiLU (ROUND-0 VERBATIM)
    lin_mfma<1, 64, 1, 1, __hip_bfloat16, float><<<NNODE / 64, 256, 0, stream>>>(
        o, Wo, nullptr, nullptr, out, nullptr, nullptr, x, gamma, beta, 0);
    // out l1/l2: overlay + NPB 16 (512 blocks each)
    lin_ovl<3, 16, __hip_bfloat16, float><<<dim3(NNODE / 16, 1), 256, 0, stream>>>(
        o, Wo + 16384, nullptr, nullptr, out, nullptr, nullptr, x, 128);
    lin_ovl<5, 16, __hip_bfloat16, float><<<dim3(NNODE / 16, 1), 256, 0, stream>>>(
        o, Wo + 32768, nullptr, nullptr, out, nullptr, nullptr, x, 512);
}

// Round 9
// 239.038 us; speedup vs baseline: 1.0506x; 1.0227x over previous
//
#include <hip/hip_runtime.h>
#include <hip/hip_bf16.h>

// Problem constants (from reference)
#define C_CH   128
#define DROW   1152          // C * (1+3+5)
#define NNODE  8192          // B*M
#define BATCH  16
#define MSEQ   512
#define NHEAD  8
#define HD     144           // DROW / NHEAD
#define NEDGE  262144

typedef unsigned short ushort_t;
typedef __attribute__((ext_vector_type(8))) short bf16x8;
typedef __attribute__((ext_vector_type(4))) float f32x4;

__device__ __forceinline__ ushort_t f2bu(float x) {
    __hip_bfloat16 h = __float2bfloat16(x);
    return *reinterpret_cast<ushort_t*>(&h);
}
__device__ __forceinline__ float bu2f(ushort_t u) {
    return __bfloat162float(*reinterpret_cast<__hip_bfloat16*>(&u));
}
// static-index halfword extract from a uint4 held in registers (no memory)
__device__ __forceinline__ unsigned u16of(const uint4 v, int ii) {
    const unsigned w = ((ii >> 1) == 0) ? v.x : ((ii >> 1) == 1) ? v.y :
                       ((ii >> 1) == 2) ? v.z : v.w;
    return (ii & 1) ? (w >> 16) : (w & 0xFFFFu);
}

#define KP2 136   // LDS row elems for K=128 (+8 pad)

// ---------------------------------------------------------------------------
// NZ=1 irreps_linear with LDS OVERLAY (R8, proven): Es reuses Xs storage.
// ---------------------------------------------------------------------------
template<int DL, int NPB, typename TX, typename TY>
__global__ __launch_bounds__(256) void lin_ovl(
    const TX* __restrict__ X,
    const float* __restrict__ W0, const float* __restrict__ W1,
    const float* __restrict__ W2,
    TY* __restrict__ Y0, TY* __restrict__ Y1, TY* __restrict__ Y2,
    const float* __restrict__ resid,
    int baseoff)
{
    constexpr int COLS = NPB * DL;     // GEMM columns per block (multiple of 16)
    constexpr int CT   = COLS / 16;
    __shared__ __align__(16) ushort_t Bs[COLS][KP2];   // Xs, then Es (overlay)

    const int tid  = threadIdx.x;
    const int wave = tid >> 6;
    const int lane = tid & 63;
    const int l15  = lane & 15;
    const int quad = lane >> 4;
    const int n0   = blockIdx.x * NPB;
    const int z    = blockIdx.y;

    const float* W = (z == 0) ? W0 : (z == 1 ? W1 : W2);
    TY* Y          = (z == 0) ? Y0 : (z == 1 ? Y1 : Y2);

    // ---- stage X^T: Bs[nb*DL + m][c] = X[n0+nb, baseoff + c*DL + m] ----
    if constexpr (sizeof(TX) == 4) {
        for (int e4 = tid; e4 < NPB * 32 * DL; e4 += 256) {
            const int nb = e4 / (32 * DL);
            const int rr = (e4 - nb * (32 * DL)) * 4;
            const float4 xv = *reinterpret_cast<const float4*>(
                &X[(size_t)(n0 + nb) * DROW + baseoff + rr]);
            #pragma unroll
            for (int j = 0; j < 4; ++j) {
                const int r = rr + j, c = r / DL, m = r - c * DL;
                Bs[nb * DL + m][c] = f2bu(reinterpret_cast<const float*>(&xv)[j]);
            }
        }
    } else {
        for (int e8 = tid; e8 < NPB * 16 * DL; e8 += 256) {
            const int nb = e8 / (16 * DL);
            const int rr = (e8 - nb * (16 * DL)) * 8;
            const uint4 xv = *reinterpret_cast<const uint4*>(
                &X[(size_t)(n0 + nb) * DROW + baseoff + rr]);
            const ushort_t* xs = reinterpret_cast<const ushort_t*>(&xv);
            #pragma unroll
            for (int j = 0; j < 8; ++j) {
                const int r = rr + j, c = r / DL, m = r - c * DL;
                Bs[nb * DL + m][c] = xs[j];
            }
        }
    }

    const float s = 0.08838834764831845f;      // 1/sqrt(128)

    // W fragments -> registers (wave owns o in [32w, 32w+32))
    bf16x8 aw[2][4];
    #pragma unroll
    for (int ot = 0; ot < 2; ++ot)
        #pragma unroll
        for (int kst = 0; kst < 4; ++kst) {
            const float* wp = &W[(size_t)(32 * wave + 16 * ot + l15) * 128 + kst * 32 + quad * 8];
            const float4 wa = *reinterpret_cast<const float4*>(wp);
            const float4 wb = *reinterpret_cast<const float4*>(wp + 4);
            ushort_t t[8] = {f2bu(wa.x), f2bu(wa.y), f2bu(wa.z), f2bu(wa.w),
                             f2bu(wb.x), f2bu(wb.y), f2bu(wb.z), f2bu(wb.w)};
            aw[ot][kst] = *reinterpret_cast<const bf16x8*>(t);
        }

    __syncthreads();   // Xs staged

    f32x4 acc[CT][2];
    #pragma unroll
    for (int ct = 0; ct < CT; ++ct) {
        acc[ct][0] = (f32x4){0.f, 0.f, 0.f, 0.f};
        acc[ct][1] = (f32x4){0.f, 0.f, 0.f, 0.f};
    }
    #pragma unroll
    for (int kst = 0; kst < 4; ++kst)
        #pragma unroll
        for (int ct = 0; ct < CT; ++ct) {
            const bf16x8 b = *reinterpret_cast<const bf16x8*>(
                &Bs[ct * 16 + l15][kst * 32 + quad * 8]);
            acc[ct][0] = __builtin_amdgcn_mfma_f32_16x16x32_bf16(aw[0][kst], b, acc[ct][0], 0, 0, 0);
            acc[ct][1] = __builtin_amdgcn_mfma_f32_16x16x32_bf16(aw[1][kst], b, acc[ct][1], 0, 0, 0);
        }

    __syncthreads();   // ALL waves done reading Xs (overlay hazard barrier)

    // C -> Es[col][o] (scale applied here), Es overlaid on Xs storage
    #pragma unroll
    for (int ct = 0; ct < CT; ++ct)
        #pragma unroll
        for (int ot = 0; ot < 2; ++ot) {
            ushort_t t[4] = {f2bu(acc[ct][ot][0] * s), f2bu(acc[ct][ot][1] * s),
                             f2bu(acc[ct][ot][2] * s), f2bu(acc[ct][ot][3] * s)};
            *reinterpret_cast<uint2*>(&Bs[ct * 16 + l15][32 * wave + 16 * ot + quad * 4]) =
                *reinterpret_cast<const uint2*>(t);
        }
    __syncthreads();   // Es visible

    // coalesced store: contiguous spans of 8 output elems r = o*DL+m
    for (int e8 = tid; e8 < COLS * 16; e8 += 256) {
        const int nb = e8 / (16 * DL);
        const int r0 = (e8 - nb * (16 * DL)) * 8;
        const size_t ga = (size_t)(n0 + nb) * DROW + baseoff + r0;
        if constexpr (sizeof(TY) == 2) {
            ushort_t t[8];
            #pragma unroll
            for (int j = 0; j < 8; ++j) {
                const int r = r0 + j;
                t[j] = Bs[nb * DL + r % DL][r / DL];
            }
            *reinterpret_cast<uint4*>(&Y[ga]) = *reinterpret_cast<const uint4*>(t);
        } else {
            #pragma unroll
            for (int j4 = 0; j4 < 2; ++j4) {
                const float4 rv = *reinterpret_cast<const float4*>(&resid[ga + j4 * 4]);
                float4 ov;
                #pragma unroll
                for (int j = 0; j < 4; ++j) {
                    const int r = r0 + j4 * 4 + j;
                    reinterpret_cast<float*>(&ov)[j] =
                        bu2f(Bs[nb * DL + r % DL][r / DL]) +
                        reinterpret_cast<const float*>(&rv)[j];
                }
                *reinterpret_cast<float4*>(&((float*)Y)[ga + j4 * 4]) = ov;
            }
        }
    }
}

// ---------------------------------------------------------------------------
// irreps_linear — round-0 body; FUSE_LN epilogue guarded by tid < NPB*4 so
// NPB=32 (256 blocks, full GPU) keeps per-node LN math BYTE-IDENTICAL to
// round 0 (4 lanes/node, same shfl groups); threads >= NPB*4 idle there.
// ---------------------------------------------------------------------------
template<int DL, int NPB, int NZ, int FUSE_LN, typename TX, typename TY>
__global__ __launch_bounds__(256) void lin_mfma(
    const TX* __restrict__ X,
    const float* __restrict__ W0, const float* __restrict__ W1,
    const float* __restrict__ W2,
    TY* __restrict__ Y0, TY* __restrict__ Y1, TY* __restrict__ Y2,
    const float* __restrict__ resid,
    const float* __restrict__ gamma, const float* __restrict__ beta,
    int baseoff)
{
    constexpr int COLS = NPB * DL;     // GEMM columns per block (multiple of 16)
    constexpr int CT   = COLS / 16;
    __shared__ __align__(16) ushort_t Xs[COLS][KP2];
    __shared__ __align__(16) ushort_t Es[COLS][KP2];

    const int tid  = threadIdx.x;
    const int wave = tid >> 6;
    const int lane = tid & 63;
    const int l15  = lane & 15;
    const int quad = lane >> 4;
    const int n0   = blockIdx.x * NPB;

    // ---- stage X^T: Xs[nb*DL + m][c] = X[n0+nb, baseoff + c*DL + m] ----
    if constexpr (sizeof(TX) == 4) {
        for (int e4 = tid; e4 < NPB * 32 * DL; e4 += 256) {
            const int nb = e4 / (32 * DL);
            const int rr = (e4 - nb * (32 * DL)) * 4;
            const float4 xv = *reinterpret_cast<const float4*>(
                &X[(size_t)(n0 + nb) * DROW + baseoff + rr]);
            #pragma unroll
            for (int j = 0; j < 4; ++j) {
                const int r = rr + j, c = r / DL, m = r - c * DL;
                Xs[nb * DL + m][c] = f2bu(reinterpret_cast<const float*>(&xv)[j]);
            }
        }
    } else {
        for (int e8 = tid; e8 < NPB * 16 * DL; e8 += 256) {
            const int nb = e8 / (16 * DL);
            const int rr = (e8 - nb * (16 * DL)) * 8;
            const uint4 xv = *reinterpret_cast<const uint4*>(
                &X[(size_t)(n0 + nb) * DROW + baseoff + rr]);
            const ushort_t* xs = reinterpret_cast<const ushort_t*>(&xv);
            #pragma unroll
            for (int j = 0; j < 8; ++j) {
                const int r = rr + j, c = r / DL, m = r - c * DL;
                Xs[nb * DL + m][c] = xs[j];
            }
        }
    }

    const float s = 0.08838834764831845f;      // 1/sqrt(128)

    for (int z = 0; z < NZ; ++z) {
        const float* W = (z == 0) ? W0 : (z == 1 ? W1 : W2);
        TY* Y          = (z == 0) ? Y0 : (z == 1 ? Y1 : Y2);

        // W fragments -> registers (wave owns o in [32w, 32w+32))
        bf16x8 aw[2][4];
        #pragma unroll
        for (int ot = 0; ot < 2; ++ot)
            #pragma unroll
            for (int kst = 0; kst < 4; ++kst) {
                const float* wp = &W[(size_t)(32 * wave + 16 * ot + l15) * 128 + kst * 32 + quad * 8];
                const float4 wa = *reinterpret_cast<const float4*>(wp);
                const float4 wb = *reinterpret_cast<const float4*>(wp + 4);
                ushort_t t[8] = {f2bu(wa.x), f2bu(wa.y), f2bu(wa.z), f2bu(wa.w),
                                 f2bu(wb.x), f2bu(wb.y), f2bu(wb.z), f2bu(wb.w)};
                aw[ot][kst] = *reinterpret_cast<const bf16x8*>(t);
            }

        __syncthreads();   // Xs staged (z=0); prev z's Es reads done (z>0)

        f32x4 acc[CT][2];
        #pragma unroll
        for (int ct = 0; ct < CT; ++ct) {
            acc[ct][0] = (f32x4){0.f, 0.f, 0.f, 0.f};
            acc[ct][1] = (f32x4){0.f, 0.f, 0.f, 0.f};
        }
        #pragma unroll
        for (int kst = 0; kst < 4; ++kst)
            #pragma unroll
            for (int ct = 0; ct < CT; ++ct) {
                const bf16x8 b = *reinterpret_cast<const bf16x8*>(
                    &Xs[ct * 16 + l15][kst * 32 + quad * 8]);
                acc[ct][0] = __builtin_amdgcn_mfma_f32_16x16x32_bf16(aw[0][kst], b, acc[ct][0], 0, 0, 0);
                acc[ct][1] = __builtin_amdgcn_mfma_f32_16x16x32_bf16(aw[1][kst], b, acc[ct][1], 0, 0, 0);
            }

        // C -> Es[col][o] (scale applied here)
        #pragma unroll
        for (int ct = 0; ct < CT; ++ct)
            #pragma unroll
            for (int ot = 0; ot < 2; ++ot) {
                ushort_t t[4] = {f2bu(acc[ct][ot][0] * s), f2bu(acc[ct][ot][1] * s),
                                 f2bu(acc[ct][ot][2] * s), f2bu(acc[ct][ot][3] * s)};
                *reinterpret_cast<uint2*>(&Es[ct * 16 + l15][32 * wave + 16 * ot + quad * 4]) =
                    *reinterpret_cast<const uint2*>(t);
            }
        __syncthreads();

        if constexpr (FUSE_LN) {
            // 4 lanes per node, 32 channels each (round-0 mapping); only
            // the first NPB*4 threads participate.
            if (tid < NPB * 4) {
                const int nb = tid >> 2, cc = tid & 3;
                float y[32];
                const float* xr = resid + (size_t)(n0 + nb) * DROW + cc * 32;
                float s1 = 0.f, s2 = 0.f;
                #pragma unroll
                for (int j4 = 0; j4 < 8; ++j4) {
                    const float4 rv = *reinterpret_cast<const float4*>(xr + j4 * 4);
                    #pragma unroll
                    for (int j = 0; j < 4; ++j) {
                        const float v = bu2f(Es[nb][cc * 32 + j4 * 4 + j]) +
                                        reinterpret_cast<const float*>(&rv)[j];
                        y[j4 * 4 + j] = v; s1 += v; s2 += v * v;
                    }
                }
                s1 += __shfl_xor(s1, 1); s2 += __shfl_xor(s2, 1);
                s1 += __shfl_xor(s1, 2); s2 += __shfl_xor(s2, 2);
                const float mean = s1 * (1.0f / 128.0f);
                const float var  = s2 * (1.0f / 128.0f) - mean * mean;
                const float rstd = rsqrtf(var + 1e-5f);
                float* op = (float*)Y + (size_t)(n0 + nb) * DROW + cc * 32;
                #pragma unroll
                for (int j4 = 0; j4 < 8; ++j4) {
                    float4 ov;
                    #pragma unroll
                    for (int j = 0; j < 4; ++j) {
                        const int c = cc * 32 + j4 * 4 + j;
                        float t = (y[j4 * 4 + j] - mean) * rstd * gamma[c] + beta[c];
                        reinterpret_cast<float*>(&ov)[j] = t / (1.0f + __expf(-t));
                    }
                    *reinterpret_cast<float4*>(op + j4 * 4) = ov;
                }
            }
        } else {
            // coalesced store: contiguous spans of 8 output elems r = o*DL+m
            for (int e8 = tid; e8 < COLS * 16; e8 += 256) {
                const int nb = e8 / (16 * DL);
                const int r0 = (e8 - nb * (16 * DL)) * 8;
                const size_t ga = (size_t)(n0 + nb) * DROW + baseoff + r0;
                if constexpr (sizeof(TY) == 2) {
                    ushort_t t[8];
                    #pragma unroll
                    for (int j = 0; j < 8; ++j) {
                        const int r = r0 + j;
                        t[j] = Es[nb * DL + r % DL][r / DL];
                    }
                    *reinterpret_cast<uint4*>(&Y[ga]) = *reinterpret_cast<const uint4*>(t);
                } else {
                    #pragma unroll
                    for (int j4 = 0; j4 < 2; ++j4) {
                        const float4 rv = *reinterpret_cast<const float4*>(&resid[ga + j4 * 4]);
                        float4 ov;
                        #pragma unroll
                        for (int j = 0; j < 4; ++j) {
                            const int r = r0 + j4 * 4 + j;
                            reinterpret_cast<float*>(&ov)[j] =
                                bu2f(Es[nb * DL + r % DL][r / DL]) +
                                reinterpret_cast<const float*>(&rv)[j];
                        }
                        *reinterpret_cast<float4*>(&((float*)Y)[ga + j4 * 4]) = ov;
                    }
                }
            }
        }
    }
}

// ---------------------------------------------------------------------------
// One-pass MFMA attention — ROUND-5 + vst XOR-swizzle (this round).
// vst write banks ignored `ga` (row-stride 144B and ga-stride 1152B are both
// ≡0 mod 128B) => ~16-way conflict on every V write, ~33% of runtime per
// SQ_LDS_BANK_CONFLICT=9.7M. Swizzle: column group rq -> rq ^ ((row>>3 & 3)
// << 2); applied at write AND read (mask even => bf16x8 read stays one
// contiguous aligned 16B). Pure storage permutation => bitwise-identical.
// Init rows 144-159 are constant per row => permutation = identity, no change.
// ---------------------------------------------------------------------------
#define KPAD  168   // ksqs row elems (144 data + 16 zero-pad + 8)
#define VROWS 160   // 144 V-cols + ones-row + 15 zero rows
#define VPAD2 72    // vst row elems (64 keys + 8)
#define PPAD  68    // ps row elems (64 keys + 4)

__global__ __launch_bounds__(256, 2) void attn_kernel(
    const __hip_bfloat16* __restrict__ Q, const __hip_bfloat16* __restrict__ K,
    const __hip_bfloat16* __restrict__ V, __hip_bfloat16* __restrict__ O)
{
    __shared__ __align__(16) ushort_t ksqs[64][KPAD];   // 21504 B
    __shared__ __align__(16) ushort_t vst[VROWS][VPAD2];// 23040 B
    __shared__ __align__(16) ushort_t ps[128][PPAD];    // 17408 B

    const int tid  = threadIdx.x;
    const int wave = tid >> 6;
    const int lane = tid & 63;
    const int l15  = lane & 15;
    const int quad = lane >> 4;

    const int bid = blockIdx.x;
    const int xcd = bid & 7;
    const int j   = bid >> 3;              // 0..63
    const int bh  = xcd * 16 + (j >> 2);   // 0..127
    const int q0  = (j & 3) * 128;
    const int h   = bh & 7;
    const int b   = bh >> 3;
    const size_t rowbase = (size_t)b * MSEQ * DROW + (size_t)h * HD;
    const float EXSCALE = 0.12022458674074695f;   // log2(e)/sqrt(144)

    // ---- per-thread staging geometry (computed once) ----
    const int r0 = tid / 18,          g0 = tid % 18;
    const int r1 = (tid + 256) / 18,  g1 = (tid + 256) % 18;
    const int r2 = (tid + 512) / 18,  g2 = (tid + 512) % 18;
    const int r3 = (tid + 768) / 18,  g3 = (tid + 768) % 18;
    const int r4 = (tid + 1024) / 18, g4 = (tid + 1024) % 18;
    const int ko0 = r0 * DROW + g0 * 8, ko1 = r1 * DROW + g1 * 8;
    const int ko2 = r2 * DROW + g2 * 8, ko3 = r3 * DROW + g3 * 8;
    const int ko4 = r4 * DROW + g4 * 8;
    ushort_t* kld0 = &ksqs[r0][g0 * 8];
    ushort_t* kld1 = &ksqs[r1][g1 * 8];
    ushort_t* kld2 = &ksqs[r2][g2 * 8];
    ushort_t* kld3 = &ksqs[r3][g3 * 8];
    ushort_t* kld4 = &ksqs[r4][g4 * 8];
    const int rqa = tid / 18,          ga = tid % 18;
    const int rqb = (tid + 256) / 18,  gb = (tid + 256) % 18;
    const int voa = (rqa * 4) * DROW + ga * 8;
    const int vob = (rqb * 4) * DROW + gb * 8;
    // swizzled column start for V writes (group rq ^ ((row>>3 &3)<<2); for
    // rows ga*8+ii, row>>3 == ga)
    const int vca = 4 * (rqa ^ ((ga & 3) << 2));
    const int vcb = 4 * (rqb ^ ((gb & 3) << 2));
    const bool hasK4 = (tid < 128);
    const bool hasVB = (tid < 32);

    uint4 kp0, kp1, kp2, kp3, kp4;
    uint4 va0, va1, va2, va3, vb0, vb1, vb2, vb3;

#define LOAD_K(KC) do { \
        const __hip_bfloat16* kb_ = K + rowbase + (size_t)((KC) * 64) * DROW; \
        kp0 = *reinterpret_cast<const uint4*>(kb_ + ko0); \
        kp1 = *reinterpret_cast<const uint4*>(kb_ + ko1); \
        kp2 = *reinterpret_cast<const uint4*>(kb_ + ko2); \
        kp3 = *reinterpret_cast<const uint4*>(kb_ + ko3); \
        if (hasK4) kp4 = *reinterpret_cast<const uint4*>(kb_ + ko4); \
    } while (0)

#define LOAD_V(KC) do { \
        const __hip_bfloat16* vbp_ = V + rowbase + (size_t)((KC) * 64) * DROW; \
        va0 = *reinterpret_cast<const uint4*>(vbp_ + voa); \
        va1 = *reinterpret_cast<const uint4*>(vbp_ + voa + DROW); \
        va2 = *reinterpret_cast<const uint4*>(vbp_ + voa + 2 * DROW); \
        va3 = *reinterpret_cast<const uint4*>(vbp_ + voa + 3 * DROW); \
        if (hasVB) { \
            vb0 = *reinterpret_cast<const uint4*>(vbp_ + vob); \
            vb1 = *reinterpret_cast<const uint4*>(vbp_ + vob + DROW); \
            vb2 = *reinterpret_cast<const uint4*>(vbp_ + vob + 2 * DROW); \
            vb3 = *reinterpret_cast<const uint4*>(vbp_ + vob + 3 * DROW); \
        } \
    } while (0)

#define WRITE_KV() do { \
        *reinterpret_cast<uint4*>(kld0) = kp0; \
        *reinterpret_cast<uint4*>(kld1) = kp1; \
        *reinterpret_cast<uint4*>(kld2) = kp2; \
        *reinterpret_cast<uint4*>(kld3) = kp3; \
        if (hasK4) *reinterpret_cast<uint4*>(kld4) = kp4; \
        _Pragma("unroll") \
        for (int ii = 0; ii < 8; ++ii) { \
            uint2 pk; \
            pk.x = u16of(va0, ii) | (u16of(va1, ii) << 16); \
            pk.y = u16of(va2, ii) | (u16of(va3, ii) << 16); \
            *reinterpret_cast<uint2*>(&vst[ga * 8 + ii][vca]) = pk; \
        } \
        if (hasVB) { \
            _Pragma("unroll") \
            for (int ii = 0; ii < 8; ++ii) { \
                uint2 pk; \
                pk.x = u16of(vb0, ii) | (u16of(vb1, ii) << 16); \
                pk.y = u16of(vb2, ii) | (u16of(vb3, ii) << 16); \
                *reinterpret_cast<uint2*>(&vst[gb * 8 + ii][vcb]) = pk; \
            } \
        } \
    } while (0)

    LOAD_K(0);
    LOAD_V(0);     // in flight across zero-init + whole Q phase

    for (int idx = tid; idx < 64 * 16; idx += 256)
        ksqs[idx >> 4][HD + (idx & 15)] = 0;
    for (int idx = tid; idx < 16 * VPAD2; idx += 256)
        vst[144 + idx / VPAD2][idx % VPAD2] = (idx / VPAD2 == 0) ? (ushort_t)0x3F80 : (ushort_t)0;
    // (rows 144-159 are constant per row; column permutation is identity)

    bf16x8 aq[2][5];
    for (int hh = 0; hh < 2; ++hh) {
        __syncthreads();
        for (int idx = tid; idx < 64 * 18; idx += 256) {
            const int r = idx / 18, g = idx % 18;
            *reinterpret_cast<uint4*>(&ksqs[r][g * 8]) =
                *reinterpret_cast<const uint4*>(&Q[rowbase + (size_t)(q0 + hh * 64 + r) * DROW + g * 8]);
        }
        __syncthreads();
        if ((wave >> 1) == hh) {
            #pragma unroll
            for (int rt = 0; rt < 2; ++rt)
                #pragma unroll
                for (int kst = 0; kst < 5; ++kst)
                    aq[rt][kst] = *reinterpret_cast<const bf16x8*>(
                        &ksqs[32 * (wave & 1) + rt * 16 + l15][kst * 32 + quad * 8]);
        }
    }

    f32x4 oacc[2][10];
    #pragma unroll
    for (int rt = 0; rt < 2; ++rt)
        #pragma unroll
        for (int nt = 0; nt < 10; ++nt) oacc[rt][nt] = (f32x4){0.f, 0.f, 0.f, 0.f};

    for (int kc = 0; kc < 8; ++kc) {
        __syncthreads();          // aq reads / prev tile's LDS reads complete
        WRITE_KV();               // staged regs -> ksqs / vst (swizzled)
        __syncthreads();          // staging visible
        if (kc < 7) LOAD_K(kc + 1);   // K loads fly under QK^T MFMAs

        f32x4 sc[2][4];
        #pragma unroll
        for (int rt = 0; rt < 2; ++rt)
            #pragma unroll
            for (int kt = 0; kt < 4; ++kt) sc[rt][kt] = (f32x4){0.f, 0.f, 0.f, 0.f};
        #pragma unroll
        for (int kst = 0; kst < 5; ++kst) {
            bf16x8 bk[4];
            #pragma unroll
            for (int kt = 0; kt < 4; ++kt)
                bk[kt] = *reinterpret_cast<const bf16x8*>(
                    &ksqs[kt * 16 + l15][kst * 32 + quad * 8]);
            #pragma unroll
            for (int rt = 0; rt < 2; ++rt)
                #pragma unroll
                for (int kt = 0; kt < 4; ++kt)
                    sc[rt][kt] = __builtin_amdgcn_mfma_f32_16x16x32_bf16(aq[rt][kst], bk[kt], sc[rt][kt], 0, 0, 0);
        }

        if (kc < 7) LOAD_V(kc + 1);   // V loads fly under exp + PV phases

        #pragma unroll
        for (int rt = 0; rt < 2; ++rt)
            #pragma unroll
            for (int kt = 0; kt < 4; ++kt)
                #pragma unroll
                for (int i = 0; i < 4; ++i)
                    ps[32 * wave + 16 * rt + quad * 4 + i][16 * kt + l15] =
                        f2bu(exp2f(sc[rt][kt][i] * EXSCALE));

        #pragma unroll
        for (int kp = 0; kp < 2; ++kp) {
            bf16x8 pa[2];
            #pragma unroll
            for (int rt = 0; rt < 2; ++rt)
                pa[rt] = *reinterpret_cast<const bf16x8*>(
                    &ps[32 * wave + 16 * rt + l15][kp * 32 + quad * 8]);
            #pragma unroll
            for (int nt = 0; nt < 10; ++nt) {
                const int vrow = nt * 16 + l15;
                const int vcol = 4 * ((kp * 8 + quad * 2) ^ (((vrow >> 3) & 3) << 2));
                const bf16x8 bv = *reinterpret_cast<const bf16x8*>(&vst[vrow][vcol]);
                #pragma unroll
                for (int rt = 0; rt < 2; ++rt)
                    oacc[rt][nt] = __builtin_amdgcn_mfma_f32_16x16x32_bf16(pa[rt], bv, oacc[rt][nt], 0, 0, 0);
            }
        }
    }

    #pragma unroll
    for (int rt = 0; rt < 2; ++rt) {
        #pragma unroll
        for (int i = 0; i < 4; ++i) {
            const float l = __shfl(oacc[rt][9][i], lane & 48);
            const float inv = 1.0f / l;
            const int row = q0 + 32 * wave + 16 * rt + quad * 4 + i;
            const size_t rb = rowbase + (size_t)row * DROW;
            #pragma unroll
            for (int nt = 0; nt < 9; ++nt)
                O[rb + nt * 16 + l15] = __float2bfloat16(oacc[rt][nt][i] * inv);
        }
    }
#undef LOAD_K
#undef LOAD_V
#undef WRITE_KV
}

// ---------------------------------------------------------------------------
// Per-edge rotation matrix (faithful port of init_edge_rot_mat).
// ---------------------------------------------------------------------------
__global__ __launch_bounds__(256) void rot_kernel(
    const float* __restrict__ ev, const float* __restrict__ er,
    float* __restrict__ rot)
{
    const int e = blockIdx.x * 256 + threadIdx.x;
    if (e >= NEDGE) return;
    const float vx = ev[e * 3 + 0], vy = ev[e * 3 + 1], vz = ev[e * 3 + 2];
    const float d = sqrtf(vx * vx + vy * vy + vz * vz);
    const float nx0 = vx / d, nx1 = vy / d, nx2 = vz / d;
    float r0 = er[e * 3 + 0] - 0.5f;
    float r1 = er[e * 3 + 1] - 0.5f;
    float r2 = er[e * 3 + 2] - 0.5f;
    const float rn = sqrtf(r0 * r0 + r1 * r1 + r2 * r2);
    r0 /= rn; r1 /= rn; r2 /= rn;
    const float b0 = -r1, b1 = r0, b2v = r2;          // e2b
    const float c0 = r0, c1 = -r2, c2 = r1;           // e2c
    const float vd0 = fabsf(r0 * nx0 + r1 * nx1 + r2 * nx2);
    const float vdb = fabsf(b0 * nx0 + b1 * nx1 + b2v * nx2);
    const float vdc = fabsf(c0 * nx0 + c1 * nx1 + c2 * nx2);
    if (vd0 > vdb) { r0 = b0; r1 = b1; r2 = b2v; }
    const float vd1 = fabsf(r0 * nx0 + r1 * nx1 + r2 * nx2);
    if (vd1 > vdc) { r0 = c0; r1 = c1; r2 = c2; }
    float z0 = nx1 * r2 - nx2 * r1;
    float z1 = nx2 * r0 - nx0 * r2;
    float z2 = nx0 * r1 - nx1 * r0;
    const float zn = sqrtf(z0 * z0 + z1 * z1 + z2 * z2);
    z0 /= zn; z1 /= zn; z2 /= zn;
    float y0 = nx1 * z2 - nx2 * z1;
    float y1 = nx2 * z0 - nx0 * z2;
    float y2 = nx0 * z1 - nx1 * z0;
    const float yn = sqrtf(y0 * y0 + y1 * y1 + y2 * y2);
    y0 /= yn; y1 /= yn; y2 /= yn;
    float* rp = rot + (size_t)e * 9;
    rp[0] = z0;   rp[1] = z1;   rp[2] = z2;
    rp[3] = nx0;  rp[4] = nx1;  rp[5] = nx2;
    rp[6] = -y0;  rp[7] = -y1;  rp[8] = -y2;
}

extern "C" void kernel_launch(void* const* d_in, const int* in_sizes, int n_in,
                              void* d_out, int out_size, void* d_ws, size_t ws_size,
                              hipStream_t stream)
{
    (void)in_sizes; (void)n_in; (void)out_size; (void)ws_size;
    const float* x     = (const float*)d_in[0];
    const float* ev    = (const float*)d_in[1];
    const float* er    = (const float*)d_in[2];
    const float* Wq    = (const float*)d_in[3];
    const float* Wk    = (const float*)d_in[4];
    const float* Wv    = (const float*)d_in[5];
    const float* Wo    = (const float*)d_in[6];
    const float* gamma = (const float*)d_in[7];
    const float* beta  = (const float*)d_in[8];
    // d_in[9] edge_index, d_in[10] batch: unused by the reference math.

    float* out = (float*)d_out;
    float* rot = out + (size_t)NNODE * DROW;

    const size_t ND = (size_t)NNODE * DROW;
    __hip_bfloat16* q = (__hip_bfloat16*)d_ws;   // 4 x N*D bf16 = 75.5 MB scratch
    __hip_bfloat16* k = q + ND;
    __hip_bfloat16* v = k + ND;
    __hip_bfloat16* o = v + ND;

    rot_kernel<<<NEDGE / 256, 256, 0, stream>>>(ev, er, rot);

    // q/k/v linears: z in grid + LDS overlay (R8 structure)
    lin_ovl<1, 32, float, __hip_bfloat16><<<dim3(NNODE / 32, 3), 256, 0, stream>>>(
        x, Wq, Wk, Wv, q, k, v, nullptr, 0);
    lin_ovl<3, 16, float, __hip_bfloat16><<<dim3(NNODE / 16, 3), 256, 0, stream>>>(
        x, Wq + 16384, Wk + 16384, Wv + 16384, q, k, v, nullptr, 128);
    lin_ovl<5, 16, float, __hip_bfloat16><<<dim3(NNODE / 16, 3), 256, 0, stream>>>(
        x, Wq + 32768, Wk + 32768, Wv + 32768, q, k, v, nullptr, 512);

    attn_kernel<<<(MSEQ / 128) * NHEAD * BATCH, 256, 0, stream>>>(q, k, v, o);

    // output linear + residual; l0 fuses LayerNorm+SiLU (NPB 32 -> 256 blocks;
    // per-node LN math byte-identical to round 0)
    lin_mfma<1, 32, 1, 1, __hip_bfloat16, float><<<NNODE / 32, 256, 0, stream>>>(
        o, Wo, nullptr, nullptr, out, nullptr, nullptr, x, gamma, beta, 0);
    // out l1/l2: overlay + NPB 16 (512 blocks each)
    lin_ovl<3, 16, __hip_bfloat16, float><<<dim3(NNODE / 16, 1), 256, 0, stream>>>(
        o, Wo + 16384, nullptr, nullptr, out, nullptr, nullptr, x, 128);
    lin_ovl<5, 16, __hip_bfloat16, float><<<dim3(NNODE / 16, 1), 256, 0, stream>>>(
        o, Wo + 32768, nullptr, nullptr, out, nullptr, nullptr, x, 512);
}

// Round 10
// 235.006 us; speedup vs baseline: 1.0687x; 1.0172x over previous
//
#include <hip/hip_runtime.h>
#include <hip/hip_bf16.h>

// Problem constants (from reference)
#define C_CH   128
#define DROW   1152          // C * (1+3+5)
#define NNODE  8192          // B*M
#define BATCH  16
#define MSEQ   512
#define NHEAD  8
#define HD     144           // DROW / NHEAD
#define NEDGE  262144

typedef unsigned short ushort_t;
typedef __attribute__((ext_vector_type(8))) short bf16x8;
typedef __attribute__((ext_vector_type(4))) float f32x4;

__device__ __forceinline__ ushort_t f2bu(float x) {
    __hip_bfloat16 h = __float2bfloat16(x);
    return *reinterpret_cast<ushort_t*>(&h);
}
__device__ __forceinline__ float bu2f(ushort_t u) {
    return __bfloat162float(*reinterpret_cast<__hip_bfloat16*>(&u));
}
// static-index halfword extract from a uint4 held in registers (no memory)
__device__ __forceinline__ unsigned u16of(const uint4 v, int ii) {
    const unsigned w = ((ii >> 1) == 0) ? v.x : ((ii >> 1) == 1) ? v.y :
                       ((ii >> 1) == 2) ? v.z : v.w;
    return (ii & 1) ? (w >> 16) : (w & 0xFFFFu);
}

#define KP2 136   // LDS row elems for K=128 (+8 pad)

// ---------------------------------------------------------------------------
// NZ=1 irreps_linear with LDS OVERLAY (R8, proven): Es reuses Xs storage.
// R10: QKV instantiations read PRE-CONVERTED bf16 x (xb) via the uint4
// staging path — no f2bu in the hot loop, half the staging bytes. Xs
// contents bitwise-identical to staging from f32 (same f2bu rounding,
// applied once in the rot tail).
// ---------------------------------------------------------------------------
template<int DL, int NPB, typename TX, typename TY>
__global__ __launch_bounds__(256) void lin_ovl(
    const TX* __restrict__ X,
    const float* __restrict__ W0, const float* __restrict__ W1,
    const float* __restrict__ W2,
    TY* __restrict__ Y0, TY* __restrict__ Y1, TY* __restrict__ Y2,
    const float* __restrict__ resid,
    int baseoff)
{
    constexpr int COLS = NPB * DL;     // GEMM columns per block (multiple of 16)
    constexpr int CT   = COLS / 16;
    __shared__ __align__(16) ushort_t Bs[COLS][KP2];   // Xs, then Es (overlay)

    const int tid  = threadIdx.x;
    const int wave = tid >> 6;
    const int lane = tid & 63;
    const int l15  = lane & 15;
    const int quad = lane >> 4;
    const int n0   = blockIdx.x * NPB;
    const int z    = blockIdx.y;

    const float* W = (z == 0) ? W0 : (z == 1 ? W1 : W2);
    TY* Y          = (z == 0) ? Y0 : (z == 1 ? Y1 : Y2);

    // ---- stage X^T: Bs[nb*DL + m][c] = X[n0+nb, baseoff + c*DL + m] ----
    if constexpr (sizeof(TX) == 4) {
        for (int e4 = tid; e4 < NPB * 32 * DL; e4 += 256) {
            const int nb = e4 / (32 * DL);
            const int rr = (e4 - nb * (32 * DL)) * 4;
            const float4 xv = *reinterpret_cast<const float4*>(
                &X[(size_t)(n0 + nb) * DROW + baseoff + rr]);
            #pragma unroll
            for (int j = 0; j < 4; ++j) {
                const int r = rr + j, c = r / DL, m = r - c * DL;
                Bs[nb * DL + m][c] = f2bu(reinterpret_cast<const float*>(&xv)[j]);
            }
        }
    } else {
        for (int e8 = tid; e8 < NPB * 16 * DL; e8 += 256) {
            const int nb = e8 / (16 * DL);
            const int rr = (e8 - nb * (16 * DL)) * 8;
            const uint4 xv = *reinterpret_cast<const uint4*>(
                &X[(size_t)(n0 + nb) * DROW + baseoff + rr]);
            const ushort_t* xs = reinterpret_cast<const ushort_t*>(&xv);
            #pragma unroll
            for (int j = 0; j < 8; ++j) {
                const int r = rr + j, c = r / DL, m = r - c * DL;
                Bs[nb * DL + m][c] = xs[j];
            }
        }
    }

    const float s = 0.08838834764831845f;      // 1/sqrt(128)

    // W fragments -> registers (wave owns o in [32w, 32w+32))
    bf16x8 aw[2][4];
    #pragma unroll
    for (int ot = 0; ot < 2; ++ot)
        #pragma unroll
        for (int kst = 0; kst < 4; ++kst) {
            const float* wp = &W[(size_t)(32 * wave + 16 * ot + l15) * 128 + kst * 32 + quad * 8];
            const float4 wa = *reinterpret_cast<const float4*>(wp);
            const float4 wb = *reinterpret_cast<const float4*>(wp + 4);
            ushort_t t[8] = {f2bu(wa.x), f2bu(wa.y), f2bu(wa.z), f2bu(wa.w),
                             f2bu(wb.x), f2bu(wb.y), f2bu(wb.z), f2bu(wb.w)};
            aw[ot][kst] = *reinterpret_cast<const bf16x8*>(t);
        }

    __syncthreads();   // Xs staged

    f32x4 acc[CT][2];
    #pragma unroll
    for (int ct = 0; ct < CT; ++ct) {
        acc[ct][0] = (f32x4){0.f, 0.f, 0.f, 0.f};
        acc[ct][1] = (f32x4){0.f, 0.f, 0.f, 0.f};
    }
    #pragma unroll
    for (int kst = 0; kst < 4; ++kst)
        #pragma unroll
        for (int ct = 0; ct < CT; ++ct) {
            const bf16x8 b = *reinterpret_cast<const bf16x8*>(
                &Bs[ct * 16 + l15][kst * 32 + quad * 8]);
            acc[ct][0] = __builtin_amdgcn_mfma_f32_16x16x32_bf16(aw[0][kst], b, acc[ct][0], 0, 0, 0);
            acc[ct][1] = __builtin_amdgcn_mfma_f32_16x16x32_bf16(aw[1][kst], b, acc[ct][1], 0, 0, 0);
        }

    __syncthreads();   // ALL waves done reading Xs (overlay hazard barrier)

    // C -> Es[col][o] (scale applied here), Es overlaid on Xs storage
    #pragma unroll
    for (int ct = 0; ct < CT; ++ct)
        #pragma unroll
        for (int ot = 0; ot < 2; ++ot) {
            ushort_t t[4] = {f2bu(acc[ct][ot][0] * s), f2bu(acc[ct][ot][1] * s),
                             f2bu(acc[ct][ot][2] * s), f2bu(acc[ct][ot][3] * s)};
            *reinterpret_cast<uint2*>(&Bs[ct * 16 + l15][32 * wave + 16 * ot + quad * 4]) =
                *reinterpret_cast<const uint2*>(t);
        }
    __syncthreads();   // Es visible

    // coalesced store: contiguous spans of 8 output elems r = o*DL+m
    for (int e8 = tid; e8 < COLS * 16; e8 += 256) {
        const int nb = e8 / (16 * DL);
        const int r0 = (e8 - nb * (16 * DL)) * 8;
        const size_t ga = (size_t)(n0 + nb) * DROW + baseoff + r0;
        if constexpr (sizeof(TY) == 2) {
            ushort_t t[8];
            #pragma unroll
            for (int j = 0; j < 8; ++j) {
                const int r = r0 + j;
                t[j] = Bs[nb * DL + r % DL][r / DL];
            }
            *reinterpret_cast<uint4*>(&Y[ga]) = *reinterpret_cast<const uint4*>(t);
        } else {
            #pragma unroll
            for (int j4 = 0; j4 < 2; ++j4) {
                const float4 rv = *reinterpret_cast<const float4*>(&resid[ga + j4 * 4]);
                float4 ov;
                #pragma unroll
                for (int j = 0; j < 4; ++j) {
                    const int r = r0 + j4 * 4 + j;
                    reinterpret_cast<float*>(&ov)[j] =
                        bu2f(Bs[nb * DL + r % DL][r / DL]) +
                        reinterpret_cast<const float*>(&rv)[j];
                }
                *reinterpret_cast<float4*>(&((float*)Y)[ga + j4 * 4]) = ov;
            }
        }
    }
}

// ---------------------------------------------------------------------------
// irreps_linear — round-0 body; FUSE_LN epilogue guarded by tid < NPB*4 so
// NPB=32 (256 blocks, full GPU) keeps per-node LN math BYTE-IDENTICAL to
// round 0 (4 lanes/node, same shfl groups); threads >= NPB*4 idle there.
// ---------------------------------------------------------------------------
template<int DL, int NPB, int NZ, int FUSE_LN, typename TX, typename TY>
__global__ __launch_bounds__(256) void lin_mfma(
    const TX* __restrict__ X,
    const float* __restrict__ W0, const float* __restrict__ W1,
    const float* __restrict__ W2,
    TY* __restrict__ Y0, TY* __restrict__ Y1, TY* __restrict__ Y2,
    const float* __restrict__ resid,
    const float* __restrict__ gamma, const float* __restrict__ beta,
    int baseoff)
{
    constexpr int COLS = NPB * DL;     // GEMM columns per block (multiple of 16)
    constexpr int CT   = COLS / 16;
    __shared__ __align__(16) ushort_t Xs[COLS][KP2];
    __shared__ __align__(16) ushort_t Es[COLS][KP2];

    const int tid  = threadIdx.x;
    const int wave = tid >> 6;
    const int lane = tid & 63;
    const int l15  = lane & 15;
    const int quad = lane >> 4;
    const int n0   = blockIdx.x * NPB;

    // ---- stage X^T: Xs[nb*DL + m][c] = X[n0+nb, baseoff + c*DL + m] ----
    if constexpr (sizeof(TX) == 4) {
        for (int e4 = tid; e4 < NPB * 32 * DL; e4 += 256) {
            const int nb = e4 / (32 * DL);
            const int rr = (e4 - nb * (32 * DL)) * 4;
            const float4 xv = *reinterpret_cast<const float4*>(
                &X[(size_t)(n0 + nb) * DROW + baseoff + rr]);
            #pragma unroll
            for (int j = 0; j < 4; ++j) {
                const int r = rr + j, c = r / DL, m = r - c * DL;
                Xs[nb * DL + m][c] = f2bu(reinterpret_cast<const float*>(&xv)[j]);
            }
        }
    } else {
        for (int e8 = tid; e8 < NPB * 16 * DL; e8 += 256) {
            const int nb = e8 / (16 * DL);
            const int rr = (e8 - nb * (16 * DL)) * 8;
            const uint4 xv = *reinterpret_cast<const uint4*>(
                &X[(size_t)(n0 + nb) * DROW + baseoff + rr]);
            const ushort_t* xs = reinterpret_cast<const ushort_t*>(&xv);
            #pragma unroll
            for (int j = 0; j < 8; ++j) {
                const int r = rr + j, c = r / DL, m = r - c * DL;
                Xs[nb * DL + m][c] = xs[j];
            }
        }
    }

    const float s = 0.08838834764831845f;      // 1/sqrt(128)

    for (int z = 0; z < NZ; ++z) {
        const float* W = (z == 0) ? W0 : (z == 1 ? W1 : W2);
        TY* Y          = (z == 0) ? Y0 : (z == 1 ? Y1 : Y2);

        // W fragments -> registers (wave owns o in [32w, 32w+32))
        bf16x8 aw[2][4];
        #pragma unroll
        for (int ot = 0; ot < 2; ++ot)
            #pragma unroll
            for (int kst = 0; kst < 4; ++kst) {
                const float* wp = &W[(size_t)(32 * wave + 16 * ot + l15) * 128 + kst * 32 + quad * 8];
                const float4 wa = *reinterpret_cast<const float4*>(wp);
                const float4 wb = *reinterpret_cast<const float4*>(wp + 4);
                ushort_t t[8] = {f2bu(wa.x), f2bu(wa.y), f2bu(wa.z), f2bu(wa.w),
                                 f2bu(wb.x), f2bu(wb.y), f2bu(wb.z), f2bu(wb.w)};
                aw[ot][kst] = *reinterpret_cast<const bf16x8*>(t);
            }

        __syncthreads();   // Xs staged (z=0); prev z's Es reads done (z>0)

        f32x4 acc[CT][2];
        #pragma unroll
        for (int ct = 0; ct < CT; ++ct) {
            acc[ct][0] = (f32x4){0.f, 0.f, 0.f, 0.f};
            acc[ct][1] = (f32x4){0.f, 0.f, 0.f, 0.f};
        }
        #pragma unroll
        for (int kst = 0; kst < 4; ++kst)
            #pragma unroll
            for (int ct = 0; ct < CT; ++ct) {
                const bf16x8 b = *reinterpret_cast<const bf16x8*>(
                    &Xs[ct * 16 + l15][kst * 32 + quad * 8]);
                acc[ct][0] = __builtin_amdgcn_mfma_f32_16x16x32_bf16(aw[0][kst], b, acc[ct][0], 0, 0, 0);
                acc[ct][1] = __builtin_amdgcn_mfma_f32_16x16x32_bf16(aw[1][kst], b, acc[ct][1], 0, 0, 0);
            }

        // C -> Es[col][o] (scale applied here)
        #pragma unroll
        for (int ct = 0; ct < CT; ++ct)
            #pragma unroll
            for (int ot = 0; ot < 2; ++ot) {
                ushort_t t[4] = {f2bu(acc[ct][ot][0] * s), f2bu(acc[ct][ot][1] * s),
                                 f2bu(acc[ct][ot][2] * s), f2bu(acc[ct][ot][3] * s)};
                *reinterpret_cast<uint2*>(&Es[ct * 16 + l15][32 * wave + 16 * ot + quad * 4]) =
                    *reinterpret_cast<const uint2*>(t);
            }
        __syncthreads();

        if constexpr (FUSE_LN) {
            // 4 lanes per node, 32 channels each (round-0 mapping); only
            // the first NPB*4 threads participate.
            if (tid < NPB * 4) {
                const int nb = tid >> 2, cc = tid & 3;
                float y[32];
                const float* xr = resid + (size_t)(n0 + nb) * DROW + cc * 32;
                float s1 = 0.f, s2 = 0.f;
                #pragma unroll
                for (int j4 = 0; j4 < 8; ++j4) {
                    const float4 rv = *reinterpret_cast<const float4*>(xr + j4 * 4);
                    #pragma unroll
                    for (int j = 0; j < 4; ++j) {
                        const float v = bu2f(Es[nb][cc * 32 + j4 * 4 + j]) +
                                        reinterpret_cast<const float*>(&rv)[j];
                        y[j4 * 4 + j] = v; s1 += v; s2 += v * v;
                    }
                }
                s1 += __shfl_xor(s1, 1); s2 += __shfl_xor(s2, 1);
                s1 += __shfl_xor(s1, 2); s2 += __shfl_xor(s2, 2);
                const float mean = s1 * (1.0f / 128.0f);
                const float var  = s2 * (1.0f / 128.0f) - mean * mean;
                const float rstd = rsqrtf(var + 1e-5f);
                float* op = (float*)Y + (size_t)(n0 + nb) * DROW + cc * 32;
                #pragma unroll
                for (int j4 = 0; j4 < 8; ++j4) {
                    float4 ov;
                    #pragma unroll
                    for (int j = 0; j < 4; ++j) {
                        const int c = cc * 32 + j4 * 4 + j;
                        float t = (y[j4 * 4 + j] - mean) * rstd * gamma[c] + beta[c];
                        reinterpret_cast<float*>(&ov)[j] = t / (1.0f + __expf(-t));
                    }
                    *reinterpret_cast<float4*>(op + j4 * 4) = ov;
                }
            }
        } else {
            // coalesced store: contiguous spans of 8 output elems r = o*DL+m
            for (int e8 = tid; e8 < COLS * 16; e8 += 256) {
                const int nb = e8 / (16 * DL);
                const int r0 = (e8 - nb * (16 * DL)) * 8;
                const size_t ga = (size_t)(n0 + nb) * DROW + baseoff + r0;
                if constexpr (sizeof(TY) == 2) {
                    ushort_t t[8];
                    #pragma unroll
                    for (int j = 0; j < 8; ++j) {
                        const int r = r0 + j;
                        t[j] = Es[nb * DL + r % DL][r / DL];
                    }
                    *reinterpret_cast<uint4*>(&Y[ga]) = *reinterpret_cast<const uint4*>(t);
                } else {
                    #pragma unroll
                    for (int j4 = 0; j4 < 2; ++j4) {
                        const float4 rv = *reinterpret_cast<const float4*>(&resid[ga + j4 * 4]);
                        float4 ov;
                        #pragma unroll
                        for (int j = 0; j < 4; ++j) {
                            const int r = r0 + j4 * 4 + j;
                            reinterpret_cast<float*>(&ov)[j] =
                                bu2f(Es[nb * DL + r % DL][r / DL]) +
                                reinterpret_cast<const float*>(&rv)[j];
                        }
                        *reinterpret_cast<float4*>(&((float*)Y)[ga + j4 * 4]) = ov;
                    }
                }
            }
        }
    }
}

// ---------------------------------------------------------------------------
// One-pass MFMA attention — ROUND-9 VERBATIM (T14 prefetch + vst XOR-swizzle).
// ---------------------------------------------------------------------------
#define KPAD  168   // ksqs row elems (144 data + 16 zero-pad + 8)
#define VROWS 160   // 144 V-cols + ones-row + 15 zero rows
#define VPAD2 72    // vst row elems (64 keys + 8)
#define PPAD  68    // ps row elems (64 keys + 4)

__global__ __launch_bounds__(256, 2) void attn_kernel(
    const __hip_bfloat16* __restrict__ Q, const __hip_bfloat16* __restrict__ K,
    const __hip_bfloat16* __restrict__ V, __hip_bfloat16* __restrict__ O)
{
    __shared__ __align__(16) ushort_t ksqs[64][KPAD];   // 21504 B
    __shared__ __align__(16) ushort_t vst[VROWS][VPAD2];// 23040 B
    __shared__ __align__(16) ushort_t ps[128][PPAD];    // 17408 B

    const int tid  = threadIdx.x;
    const int wave = tid >> 6;
    const int lane = tid & 63;
    const int l15  = lane & 15;
    const int quad = lane >> 4;

    const int bid = blockIdx.x;
    const int xcd = bid & 7;
    const int j   = bid >> 3;              // 0..63
    const int bh  = xcd * 16 + (j >> 2);   // 0..127
    const int q0  = (j & 3) * 128;
    const int h   = bh & 7;
    const int b   = bh >> 3;
    const size_t rowbase = (size_t)b * MSEQ * DROW + (size_t)h * HD;
    const float EXSCALE = 0.12022458674074695f;   // log2(e)/sqrt(144)

    // ---- per-thread staging geometry (computed once) ----
    const int r0 = tid / 18,          g0 = tid % 18;
    const int r1 = (tid + 256) / 18,  g1 = (tid + 256) % 18;
    const int r2 = (tid + 512) / 18,  g2 = (tid + 512) % 18;
    const int r3 = (tid + 768) / 18,  g3 = (tid + 768) % 18;
    const int r4 = (tid + 1024) / 18, g4 = (tid + 1024) % 18;
    const int ko0 = r0 * DROW + g0 * 8, ko1 = r1 * DROW + g1 * 8;
    const int ko2 = r2 * DROW + g2 * 8, ko3 = r3 * DROW + g3 * 8;
    const int ko4 = r4 * DROW + g4 * 8;
    ushort_t* kld0 = &ksqs[r0][g0 * 8];
    ushort_t* kld1 = &ksqs[r1][g1 * 8];
    ushort_t* kld2 = &ksqs[r2][g2 * 8];
    ushort_t* kld3 = &ksqs[r3][g3 * 8];
    ushort_t* kld4 = &ksqs[r4][g4 * 8];
    const int rqa = tid / 18,          ga = tid % 18;
    const int rqb = (tid + 256) / 18,  gb = (tid + 256) % 18;
    const int voa = (rqa * 4) * DROW + ga * 8;
    const int vob = (rqb * 4) * DROW + gb * 8;
    // swizzled column start for V writes (group rq ^ ((row>>3 &3)<<2); for
    // rows ga*8+ii, row>>3 == ga)
    const int vca = 4 * (rqa ^ ((ga & 3) << 2));
    const int vcb = 4 * (rqb ^ ((gb & 3) << 2));
    const bool hasK4 = (tid < 128);
    const bool hasVB = (tid < 32);

    uint4 kp0, kp1, kp2, kp3, kp4;
    uint4 va0, va1, va2, va3, vb0, vb1, vb2, vb3;

#define LOAD_K(KC) do { \
        const __hip_bfloat16* kb_ = K + rowbase + (size_t)((KC) * 64) * DROW; \
        kp0 = *reinterpret_cast<const uint4*>(kb_ + ko0); \
        kp1 = *reinterpret_cast<const uint4*>(kb_ + ko1); \
        kp2 = *reinterpret_cast<const uint4*>(kb_ + ko2); \
        kp3 = *reinterpret_cast<const uint4*>(kb_ + ko3); \
        if (hasK4) kp4 = *reinterpret_cast<const uint4*>(kb_ + ko4); \
    } while (0)

#define LOAD_V(KC) do { \
        const __hip_bfloat16* vbp_ = V + rowbase + (size_t)((KC) * 64) * DROW; \
        va0 = *reinterpret_cast<const uint4*>(vbp_ + voa); \
        va1 = *reinterpret_cast<const uint4*>(vbp_ + voa + DROW); \
        va2 = *reinterpret_cast<const uint4*>(vbp_ + voa + 2 * DROW); \
        va3 = *reinterpret_cast<const uint4*>(vbp_ + voa + 3 * DROW); \
        if (hasVB) { \
            vb0 = *reinterpret_cast<const uint4*>(vbp_ + vob); \
            vb1 = *reinterpret_cast<const uint4*>(vbp_ + vob + DROW); \
            vb2 = *reinterpret_cast<const uint4*>(vbp_ + vob + 2 * DROW); \
            vb3 = *reinterpret_cast<const uint4*>(vbp_ + vob + 3 * DROW); \
        } \
    } while (0)

#define WRITE_KV() do { \
        *reinterpret_cast<uint4*>(kld0) = kp0; \
        *reinterpret_cast<uint4*>(kld1) = kp1; \
        *reinterpret_cast<uint4*>(kld2) = kp2; \
        *reinterpret_cast<uint4*>(kld3) = kp3; \
        if (hasK4) *reinterpret_cast<uint4*>(kld4) = kp4; \
        _Pragma("unroll") \
        for (int ii = 0; ii < 8; ++ii) { \
            uint2 pk; \
            pk.x = u16of(va0, ii) | (u16of(va1, ii) << 16); \
            pk.y = u16of(va2, ii) | (u16of(va3, ii) << 16); \
            *reinterpret_cast<uint2*>(&vst[ga * 8 + ii][vca]) = pk; \
        } \
        if (hasVB) { \
            _Pragma("unroll") \
            for (int ii = 0; ii < 8; ++ii) { \
                uint2 pk; \
                pk.x = u16of(vb0, ii) | (u16of(vb1, ii) << 16); \
                pk.y = u16of(vb2, ii) | (u16of(vb3, ii) << 16); \
                *reinterpret_cast<uint2*>(&vst[gb * 8 + ii][vcb]) = pk; \
            } \
        } \
    } while (0)

    LOAD_K(0);
    LOAD_V(0);     // in flight across zero-init + whole Q phase

    for (int idx = tid; idx < 64 * 16; idx += 256)
        ksqs[idx >> 4][HD + (idx & 15)] = 0;
    for (int idx = tid; idx < 16 * VPAD2; idx += 256)
        vst[144 + idx / VPAD2][idx % VPAD2] = (idx / VPAD2 == 0) ? (ushort_t)0x3F80 : (ushort_t)0;
    // (rows 144-159 are constant per row; column permutation is identity)

    bf16x8 aq[2][5];
    for (int hh = 0; hh < 2; ++hh) {
        __syncthreads();
        for (int idx = tid; idx < 64 * 18; idx += 256) {
            const int r = idx / 18, g = idx % 18;
            *reinterpret_cast<uint4*>(&ksqs[r][g * 8]) =
                *reinterpret_cast<const uint4*>(&Q[rowbase + (size_t)(q0 + hh * 64 + r) * DROW + g * 8]);
        }
        __syncthreads();
        if ((wave >> 1) == hh) {
            #pragma unroll
            for (int rt = 0; rt < 2; ++rt)
                #pragma unroll
                for (int kst = 0; kst < 5; ++kst)
                    aq[rt][kst] = *reinterpret_cast<const bf16x8*>(
                        &ksqs[32 * (wave & 1) + rt * 16 + l15][kst * 32 + quad * 8]);
        }
    }

    f32x4 oacc[2][10];
    #pragma unroll
    for (int rt = 0; rt < 2; ++rt)
        #pragma unroll
        for (int nt = 0; nt < 10; ++nt) oacc[rt][nt] = (f32x4){0.f, 0.f, 0.f, 0.f};

    for (int kc = 0; kc < 8; ++kc) {
        __syncthreads();          // aq reads / prev tile's LDS reads complete
        WRITE_KV();               // staged regs -> ksqs / vst (swizzled)
        __syncthreads();          // staging visible
        if (kc < 7) LOAD_K(kc + 1);   // K loads fly under QK^T MFMAs

        f32x4 sc[2][4];
        #pragma unroll
        for (int rt = 0; rt < 2; ++rt)
            #pragma unroll
            for (int kt = 0; kt < 4; ++kt) sc[rt][kt] = (f32x4){0.f, 0.f, 0.f, 0.f};
        #pragma unroll
        for (int kst = 0; kst < 5; ++kst) {
            bf16x8 bk[4];
            #pragma unroll
            for (int kt = 0; kt < 4; ++kt)
                bk[kt] = *reinterpret_cast<const bf16x8*>(
                    &ksqs[kt * 16 + l15][kst * 32 + quad * 8]);
            #pragma unroll
            for (int rt = 0; rt < 2; ++rt)
                #pragma unroll
                for (int kt = 0; kt < 4; ++kt)
                    sc[rt][kt] = __builtin_amdgcn_mfma_f32_16x16x32_bf16(aq[rt][kst], bk[kt], sc[rt][kt], 0, 0, 0);
        }

        if (kc < 7) LOAD_V(kc + 1);   // V loads fly under exp + PV phases

        #pragma unroll
        for (int rt = 0; rt < 2; ++rt)
            #pragma unroll
            for (int kt = 0; kt < 4; ++kt)
                #pragma unroll
                for (int i = 0; i < 4; ++i)
                    ps[32 * wave + 16 * rt + quad * 4 + i][16 * kt + l15] =
                        f2bu(exp2f(sc[rt][kt][i] * EXSCALE));

        #pragma unroll
        for (int kp = 0; kp < 2; ++kp) {
            bf16x8 pa[2];
            #pragma unroll
            for (int rt = 0; rt < 2; ++rt)
                pa[rt] = *reinterpret_cast<const bf16x8*>(
                    &ps[32 * wave + 16 * rt + l15][kp * 32 + quad * 8]);
            #pragma unroll
            for (int nt = 0; nt < 10; ++nt) {
                const int vrow = nt * 16 + l15;
                const int vcol = 4 * ((kp * 8 + quad * 2) ^ (((vrow >> 3) & 3) << 2));
                const bf16x8 bv = *reinterpret_cast<const bf16x8*>(&vst[vrow][vcol]);
                #pragma unroll
                for (int rt = 0; rt < 2; ++rt)
                    oacc[rt][nt] = __builtin_amdgcn_mfma_f32_16x16x32_bf16(pa[rt], bv, oacc[rt][nt], 0, 0, 0);
            }
        }
    }

    #pragma unroll
    for (int rt = 0; rt < 2; ++rt) {
        #pragma unroll
        for (int i = 0; i < 4; ++i) {
            const float l = __shfl(oacc[rt][9][i], lane & 48);
            const float inv = 1.0f / l;
            const int row = q0 + 32 * wave + 16 * rt + quad * 4 + i;
            const size_t rb = rowbase + (size_t)row * DROW;
            #pragma unroll
            for (int nt = 0; nt < 9; ++nt)
                O[rb + nt * 16 + l15] = __float2bfloat16(oacc[rt][nt][i] * inv);
        }
    }
#undef LOAD_K
#undef LOAD_V
#undef WRITE_KV
}

// ---------------------------------------------------------------------------
// Per-edge rotation matrix + x -> bf16 pre-conversion tail (R10).
// bx < 1024: rot (round-0 math, verbatim). bx >= 1024: grid-stride convert
// x (f32) to xb (bf16) with the same f2bu rounding the lin staging used.
// 1152 conv blocks * 256 threads * 8 float4 = exactly NNODE*DROW elems.
// ---------------------------------------------------------------------------
#define ROT_BLOCKS  (NEDGE / 256)   // 1024
#define CONV_BLOCKS 1152

__global__ __launch_bounds__(256) void rot_conv_kernel(
    const float* __restrict__ ev, const float* __restrict__ er,
    float* __restrict__ rot,
    const float* __restrict__ x, __hip_bfloat16* __restrict__ xb)
{
    const int bx = blockIdx.x;
    if (bx >= ROT_BLOCKS) {
        // ---- conversion tail ----
        const int t = (bx - ROT_BLOCKS) * 256 + threadIdx.x;   // 0..294911
        const float4* X4 = reinterpret_cast<const float4*>(x);
        uint2* XB2 = reinterpret_cast<uint2*>(xb);
        const int NV4 = NNODE * DROW / 4;          // 2359296
        const int NTH = CONV_BLOCKS * 256;         // 294912
        #pragma unroll
        for (int it = 0; it < 8; ++it) {
            const int i = t + it * NTH;
            (void)NV4;
            const float4 v = X4[i];
            uint2 o;
            o.x = (unsigned)f2bu(v.x) | ((unsigned)f2bu(v.y) << 16);
            o.y = (unsigned)f2bu(v.z) | ((unsigned)f2bu(v.w) << 16);
            XB2[i] = o;
        }
        return;
    }
    const int e = bx * 256 + threadIdx.x;
    if (e >= NEDGE) return;
    const float vx = ev[e * 3 + 0], vy = ev[e * 3 + 1], vz = ev[e * 3 + 2];
    const float d = sqrtf(vx * vx + vy * vy + vz * vz);
    const float nx0 = vx / d, nx1 = vy / d, nx2 = vz / d;
    float r0 = er[e * 3 + 0] - 0.5f;
    float r1 = er[e * 3 + 1] - 0.5f;
    float r2 = er[e * 3 + 2] - 0.5f;
    const float rn = sqrtf(r0 * r0 + r1 * r1 + r2 * r2);
    r0 /= rn; r1 /= rn; r2 /= rn;
    const float b0 = -r1, b1 = r0, b2v = r2;          // e2b
    const float c0 = r0, c1 = -r2, c2 = r1;           // e2c
    const float vd0 = fabsf(r0 * nx0 + r1 * nx1 + r2 * nx2);
    const float vdb = fabsf(b0 * nx0 + b1 * nx1 + b2v * nx2);
    const float vdc = fabsf(c0 * nx0 + c1 * nx1 + c2 * nx2);
    if (vd0 > vdb) { r0 = b0; r1 = b1; r2 = b2v; }
    const float vd1 = fabsf(r0 * nx0 + r1 * nx1 + r2 * nx2);
    if (vd1 > vdc) { r0 = c0; r1 = c1; r2 = c2; }
    float z0 = nx1 * r2 - nx2 * r1;
    float z1 = nx2 * r0 - nx0 * r2;
    float z2 = nx0 * r1 - nx1 * r0;
    const float zn = sqrtf(z0 * z0 + z1 * z1 + z2 * z2);
    z0 /= zn; z1 /= zn; z2 /= zn;
    float y0 = nx1 * z2 - nx2 * z1;
    float y1 = nx2 * z0 - nx0 * z2;
    float y2 = nx0 * z1 - nx1 * z0;
    const float yn = sqrtf(y0 * y0 + y1 * y1 + y2 * y2);
    y0 /= yn; y1 /= yn; y2 /= yn;
    float* rp = rot + (size_t)e * 9;
    rp[0] = z0;   rp[1] = z1;   rp[2] = z2;
    rp[3] = nx0;  rp[4] = nx1;  rp[5] = nx2;
    rp[6] = -y0;  rp[7] = -y1;  rp[8] = -y2;
}

extern "C" void kernel_launch(void* const* d_in, const int* in_sizes, int n_in,
                              void* d_out, int out_size, void* d_ws, size_t ws_size,
                              hipStream_t stream)
{
    (void)in_sizes; (void)n_in; (void)out_size; (void)ws_size;
    const float* x     = (const float*)d_in[0];
    const float* ev    = (const float*)d_in[1];
    const float* er    = (const float*)d_in[2];
    const float* Wq    = (const float*)d_in[3];
    const float* Wk    = (const float*)d_in[4];
    const float* Wv    = (const float*)d_in[5];
    const float* Wo    = (const float*)d_in[6];
    const float* gamma = (const float*)d_in[7];
    const float* beta  = (const float*)d_in[8];
    // d_in[9] edge_index, d_in[10] batch: unused by the reference math.

    float* out = (float*)d_out;
    float* rot = out + (size_t)NNODE * DROW;

    const size_t ND = (size_t)NNODE * DROW;
    __hip_bfloat16* q = (__hip_bfloat16*)d_ws;   // 4 x N*D bf16 = 75.5 MB scratch
    __hip_bfloat16* k = q + ND;
    __hip_bfloat16* v = k + ND;
    __hip_bfloat16* o = v + ND;
    // xb (pre-converted bf16 x) ALIASES o: o is only written by attn, which
    // runs after the QKV linears (single stream) -> no extra workspace.
    __hip_bfloat16* xb = o;

    // rot + x->bf16 conversion in one dispatch
    rot_conv_kernel<<<ROT_BLOCKS + CONV_BLOCKS, 256, 0, stream>>>(
        ev, er, rot, x, xb);

    // q/k/v linears: z in grid + LDS overlay, staging from bf16 xb
    // (bitwise-identical Xs; half the staging bytes, no cvt VALU)
    lin_ovl<1, 32, __hip_bfloat16, __hip_bfloat16><<<dim3(NNODE / 32, 3), 256, 0, stream>>>(
        xb, Wq, Wk, Wv, q, k, v, nullptr, 0);
    lin_ovl<3, 16, __hip_bfloat16, __hip_bfloat16><<<dim3(NNODE / 16, 3), 256, 0, stream>>>(
        xb, Wq + 16384, Wk + 16384, Wv + 16384, q, k, v, nullptr, 128);
    lin_ovl<5, 16, __hip_bfloat16, __hip_bfloat16><<<dim3(NNODE / 16, 3), 256, 0, stream>>>(
        xb, Wq + 32768, Wk + 32768, Wv + 32768, q, k, v, nullptr, 512);

    attn_kernel<<<(MSEQ / 128) * NHEAD * BATCH, 256, 0, stream>>>(q, k, v, o);

    // output linear + residual; l0 fuses LayerNorm+SiLU (NPB 32 -> 256 blocks)
    lin_mfma<1, 32, 1, 1, __hip_bfloat16, float><<<NNODE / 32, 256, 0, stream>>>(
        o, Wo, nullptr, nullptr, out, nullptr, nullptr, x, gamma, beta, 0);
    // out l1/l2: overlay + NPB 16 (512 blocks each)
    lin_ovl<3, 16, __hip_bfloat16, float><<<dim3(NNODE / 16, 1), 256, 0, stream>>>(
        o, Wo + 16384, nullptr, nullptr, out, nullptr, nullptr, x, 128);
    lin_ovl<5, 16, __hip_bfloat16, float><<<dim3(NNODE / 16, 1), 256, 0, stream>>>(
        o, Wo + 32768, nullptr, nullptr, out, nullptr, nullptr, x, 512);
}